// Round 1
// baseline (1404.521 us; speedup 1.0000x reference)
//
#include <hip/hip_runtime.h>
#include <math.h>

#define N_PTS 131072
#define HID 256
#define H2 512
#define H4 1024
#define GRIDW 64
#define K1 384          // 2 * 3 * 64 fourier features
#define TILE 64         // points per block
#define LN_EPS 1e-5f
#define OMEGA 30.0f

typedef __bf16 b16x8 __attribute__((ext_vector_type(8)));
typedef __bf16 b16x4 __attribute__((ext_vector_type(4)));
typedef float f32x4 __attribute__((ext_vector_type(4)));

// bf16 weight workspace layout (element offsets)
#define OFF_FC 0
#define N_FC   (HID * K1)            // 98304   fcW[256][384]
#define OFF_W1 (OFF_FC + N_FC)       // 98304   w1[512][256]
#define N_W1   (H2 * HID)            // 131072
#define OFF_W2 (OFF_W1 + N_W1)       // 229376  w2[512][512]
#define N_W2   (H2 * H2)             // 262144
#define OFF_W3 (OFF_W2 + N_W2)       // 491520  w3[512][512]
#define OFF_W4 (OFF_W3 + N_W2)       // 753664  w4[1024][512]
#define N_W4   (H4 * H2)             // 524288
#define N_TOTAL (OFF_W4 + N_W4)      // 1277952 elements (~2.44 MB bf16)

// ---------------- weight bf16 prep ----------------
__global__ void prep_kernel(const float* __restrict__ fc, const float* __restrict__ w1,
                            const float* __restrict__ w2, const float* __restrict__ w3,
                            const float* __restrict__ w4, __bf16* __restrict__ ws) {
  int idx = blockIdx.x * blockDim.x + threadIdx.x;
  if (idx >= N_TOTAL) return;
  float v;
  if (idx < OFF_W1) {
    // fcW[o][k], k = s*192 + i*64 + g  <-  fc[s][o][i][g], fc shape (2,256,3,64)
    int o = idx / K1, r = idx % K1;
    int s = r / 192, rem = r % 192, i = rem / GRIDW, g = rem % GRIDW;
    v = fc[((s * HID + o) * 3 + i) * GRIDW + g];
  } else if (idx < OFF_W3) {
    v = (idx < OFF_W2) ? w1[idx - OFF_W1] : w2[idx - OFF_W2];
  } else {
    v = (idx < OFF_W4) ? w3[idx - OFF_W3] : w4[idx - OFF_W4];
  }
  ws[idx] = (__bf16)v;
}

// ---------------- fused INR kernel ----------------
// LDS act tiles: [64 points][512 ch] bf16, row stride 1024 B.
// XOR swizzle byte ^= ((n&7)<<4) at 16B granularity (T2) to break the
// stride-1024B bank conflict on ds_read_b128 across 16 rows.

__device__ __forceinline__ float actfn(float z) {
  float t = tanhf(OMEGA * z);
  float s = 1.0f / (1.0f + expf(-z));
  return (z + t) * s;
}

__device__ __forceinline__ void store_act4(unsigned char* sY, int n, int o0,
                                           float a0, float a1, float a2, float a3) {
  b16x4 h;
  h[0] = (__bf16)a0; h[1] = (__bf16)a1; h[2] = (__bf16)a2; h[3] = (__bf16)a3;
  *(b16x4*)(sY + n * 1024 + ((o0 * 2) ^ ((n & 7) << 4))) = h;
}

// C[n, o_base + 0..16*OT) for n in 0..63:  D = W . X^T via mfma(Wfrag, Xfrag)
// D layout: row = o = (lane>>4)*4 + reg (+16*ot), col = n = lane&15 (+16*nt)
template <int K, int OT>
__device__ __forceinline__ void gemm_kloop(const unsigned char* sX, const __bf16* __restrict__ W,
                                           int lane, int o_base, f32x4 (&acc)[OT][4]) {
  const int l15 = lane & 15, lh = lane >> 4;
#pragma unroll 2
  for (int ks = 0; ks < K / 32; ++ks) {
    b16x8 xf[4];
#pragma unroll
    for (int nt = 0; nt < 4; ++nt) {
      int n = nt * 16 + l15;
      int kb = ks * 64 + (lh << 4);  // byte offset in row
      xf[nt] = *(const b16x8*)(sX + n * 1024 + (kb ^ ((n & 7) << 4)));
    }
    b16x8 wf[OT];
#pragma unroll
    for (int ot = 0; ot < OT; ++ot) {
      int o = o_base + ot * 16 + l15;
      wf[ot] = *(const b16x8*)(W + (size_t)o * K + ks * 32 + (lh << 3));
    }
#pragma unroll
    for (int ot = 0; ot < OT; ++ot)
#pragma unroll
      for (int nt = 0; nt < 4; ++nt)
        acc[ot][nt] = __builtin_amdgcn_mfma_f32_16x16x32_bf16(wf[ot], xf[nt], acc[ot][nt], 0, 0, 0);
  }
}

// one sine layer: read sX (K ch), write sY (512 ch), M = 512, 8 waves * OT=4
template <int K>
__device__ __forceinline__ void sine_layer(const unsigned char* sX, unsigned char* sY,
                                           const __bf16* __restrict__ W,
                                           const float* __restrict__ bias, int lane, int wid) {
  f32x4 acc[4][4] = {};
  const int o_base = wid * 64;
  gemm_kloop<K, 4>(sX, W, lane, o_base, acc);
  const int l15 = lane & 15, lh = lane >> 4;
#pragma unroll
  for (int ot = 0; ot < 4; ++ot) {
    int o0 = o_base + ot * 16 + (lh << 2);
    f32x4 bia = *(const f32x4*)(bias + o0);
#pragma unroll
    for (int nt = 0; nt < 4; ++nt) {
      int n = nt * 16 + l15;
      store_act4(sY, n, o0,
                 actfn(acc[ot][nt][0] + bia[0]), actfn(acc[ot][nt][1] + bia[1]),
                 actfn(acc[ot][nt][2] + bia[2]), actfn(acc[ot][nt][3] + bia[3]));
    }
  }
}

__global__ __launch_bounds__(512) void fkan_inr_kernel(
    const float* __restrict__ coords, const float* __restrict__ fkan_bias,
    const float* __restrict__ ln_g, const float* __restrict__ ln_b,
    const float* __restrict__ b1, const float* __restrict__ b2,
    const float* __restrict__ b3, const float* __restrict__ b4,
    const float* __restrict__ wout, const float* __restrict__ bout,
    const __bf16* __restrict__ ws, float* __restrict__ out) {
  __shared__ __align__(16) unsigned char sA[TILE * 1024];
  __shared__ __align__(16) unsigned char sB[TILE * 1024];
  __shared__ float sSum[TILE], sSqs[TILE];
  __shared__ float sOutF[TILE][4];

  const int tid = threadIdx.x;
  const int lane = tid & 63, wid = tid >> 6;
  const int l15 = lane & 15, lh = lane >> 4;
  const int base_n = blockIdx.x * TILE;

  // ---- Phase F: fourier features -> sA[n][k], k<384 ; zero LN stats
  if (tid < TILE) { sSum[tid] = 0.f; sSqs[tid] = 0.f; }
#pragma unroll
  for (int p = 0; p < 3; ++p) {
    int id = tid + p * 512;               // 0..1535 = (n, i, gchunk of 8)
    int n = id / 24, rem = id % 24, i = rem >> 3, g0 = (rem & 7) * 8;
    float c = coords[(base_n + n) * 3 + i];
    b16x8 cv, sv;
#pragma unroll
    for (int j = 0; j < 8; ++j) {
      float ang = c * (float)(g0 + j + 1);
      float s, co;
      sincosf(ang, &s, &co);
      cv[j] = (__bf16)co;
      sv[j] = (__bf16)s;
    }
    int kc = (i * GRIDW + g0) * 2;
    *(b16x8*)(sA + n * 1024 + (kc ^ ((n & 7) << 4))) = cv;
    int ks2 = (192 + i * GRIDW + g0) * 2;
    *(b16x8*)(sA + n * 1024 + (ks2 ^ ((n & 7) << 4))) = sv;
  }
  __syncthreads();

  // ---- GEMM1 (384 -> 256) + fkan_bias + LayerNorm -> sB
  {
    f32x4 acc[2][4] = {};
    const int o_base = wid * 32;
    gemm_kloop<K1, 2>(sA, ws + OFF_FC, lane, o_base, acc);
#pragma unroll
    for (int ot = 0; ot < 2; ++ot) {
      int o0 = o_base + ot * 16 + (lh << 2);
      f32x4 bia = *(const f32x4*)(fkan_bias + o0);
#pragma unroll
      for (int nt = 0; nt < 4; ++nt) acc[ot][nt] += bia;
    }
#pragma unroll
    for (int nt = 0; nt < 4; ++nt) {
      float s = 0.f, q = 0.f;
#pragma unroll
      for (int ot = 0; ot < 2; ++ot)
#pragma unroll
        for (int r = 0; r < 4; ++r) { float z = acc[ot][nt][r]; s += z; q += z * z; }
      s += __shfl_xor(s, 16); q += __shfl_xor(q, 16);
      s += __shfl_xor(s, 32); q += __shfl_xor(q, 32);
      if (lane < 16) {
        atomicAdd(&sSum[nt * 16 + lane], s);
        atomicAdd(&sSqs[nt * 16 + lane], q);
      }
    }
    __syncthreads();
#pragma unroll
    for (int nt = 0; nt < 4; ++nt) {
      int n = nt * 16 + l15;
      float mu = sSum[n] * (1.f / HID);
      float var = sSqs[n] * (1.f / HID) - mu * mu;
      float rs = rsqrtf(var + LN_EPS);
#pragma unroll
      for (int ot = 0; ot < 2; ++ot) {
        int o0 = o_base + ot * 16 + (lh << 2);
        f32x4 g4 = *(const f32x4*)(ln_g + o0);
        f32x4 bb = *(const f32x4*)(ln_b + o0);
        store_act4(sB, n, o0,
                   (acc[ot][nt][0] - mu) * rs * g4[0] + bb[0],
                   (acc[ot][nt][1] - mu) * rs * g4[1] + bb[1],
                   (acc[ot][nt][2] - mu) * rs * g4[2] + bb[2],
                   (acc[ot][nt][3] - mu) * rs * g4[3] + bb[3]);
      }
    }
    __syncthreads();
  }

  // ---- sine layers 1..3
  sine_layer<HID>(sB, sA, ws + OFF_W1, b1, lane, wid);
  __syncthreads();
  sine_layer<H2>(sA, sB, ws + OFF_W2, b2, lane, wid);
  __syncthreads();
  sine_layer<H2>(sB, sA, ws + OFF_W3, b3, lane, wid);
  if (tid < TILE) { sOutF[tid][0] = 0.f; sOutF[tid][1] = 0.f; sOutF[tid][2] = 0.f; sOutF[tid][3] = 0.f; }
  __syncthreads();

  // ---- layer 4 (512 -> 1024) fused with output projection (1024 -> 3)
  {
    float pj[4][3] = {};
#pragma unroll
    for (int pass = 0; pass < 2; ++pass) {
      f32x4 acc[4][4] = {};
      int o_base = wid * 128 + pass * 64;
      gemm_kloop<H2, 4>(sA, ws + OFF_W4, lane, o_base, acc);
#pragma unroll
      for (int ot = 0; ot < 4; ++ot) {
        int o0 = o_base + ot * 16 + (lh << 2);
        f32x4 bia = *(const f32x4*)(b4 + o0);
        f32x4 wo0 = *(const f32x4*)(wout + 0 * H4 + o0);
        f32x4 wo1 = *(const f32x4*)(wout + 1 * H4 + o0);
        f32x4 wo2 = *(const f32x4*)(wout + 2 * H4 + o0);
#pragma unroll
        for (int nt = 0; nt < 4; ++nt) {
          float a0 = actfn(acc[ot][nt][0] + bia[0]);
          float a1 = actfn(acc[ot][nt][1] + bia[1]);
          float a2 = actfn(acc[ot][nt][2] + bia[2]);
          float a3 = actfn(acc[ot][nt][3] + bia[3]);
          pj[nt][0] += a0 * wo0[0] + a1 * wo0[1] + a2 * wo0[2] + a3 * wo0[3];
          pj[nt][1] += a0 * wo1[0] + a1 * wo1[1] + a2 * wo1[2] + a3 * wo1[3];
          pj[nt][2] += a0 * wo2[0] + a1 * wo2[1] + a2 * wo2[2] + a3 * wo2[3];
        }
      }
    }
#pragma unroll
    for (int nt = 0; nt < 4; ++nt)
#pragma unroll
      for (int j = 0; j < 3; ++j) {
        float r = pj[nt][j];
        r += __shfl_xor(r, 16);
        r += __shfl_xor(r, 32);
        if (lane < 16) atomicAdd(&sOutF[nt * 16 + lane][j], r);
      }
    __syncthreads();
    if (tid < TILE * 3) {
      int n = tid / 3, j = tid % 3;
      out[(base_n + n) * 3 + j] = sOutF[n][j] + bout[j];
    }
  }
}

extern "C" void kernel_launch(void* const* d_in, const int* in_sizes, int n_in,
                              void* d_out, int out_size, void* d_ws, size_t ws_size,
                              hipStream_t stream) {
  const float* coords    = (const float*)d_in[0];
  const float* fc        = (const float*)d_in[1];
  const float* fkan_bias = (const float*)d_in[2];
  const float* ln_g      = (const float*)d_in[3];
  const float* ln_b      = (const float*)d_in[4];
  const float* w1        = (const float*)d_in[5];
  const float* b1        = (const float*)d_in[6];
  const float* w2        = (const float*)d_in[7];
  const float* b2        = (const float*)d_in[8];
  const float* w3        = (const float*)d_in[9];
  const float* b3        = (const float*)d_in[10];
  const float* w4        = (const float*)d_in[11];
  const float* b4        = (const float*)d_in[12];
  const float* wout      = (const float*)d_in[13];
  const float* bout      = (const float*)d_in[14];
  float* out = (float*)d_out;
  __bf16* ws = (__bf16*)d_ws;

  prep_kernel<<<(N_TOTAL + 255) / 256, 256, 0, stream>>>(fc, w1, w2, w3, w4, ws);
  fkan_inr_kernel<<<N_PTS / TILE, 512, 0, stream>>>(coords, fkan_bias, ln_g, ln_b,
                                                    b1, b2, b3, b4, wout, bout, ws, out);
}

// Round 2
// 859.708 us; speedup vs baseline: 1.6337x; 1.6337x over previous
//
#include <hip/hip_runtime.h>
#include <math.h>

#define N_PTS 131072
#define HID 256
#define H2 512
#define H4 1024
#define GRIDW 64
#define K1 384          // 2 * 3 * 64 fourier features
#define TILE 64         // points per block
#define LN_EPS 1e-5f
#define OMEGA 30.0f

typedef __bf16 b16x8 __attribute__((ext_vector_type(8)));
typedef __bf16 b16x4 __attribute__((ext_vector_type(4)));
typedef float f32x4 __attribute__((ext_vector_type(4)));

// bf16 weight workspace layout (element offsets)
#define OFF_FC 0
#define N_FC   (HID * K1)            // 98304   fcW[256][384]
#define OFF_W1 (OFF_FC + N_FC)       // 98304   w1[512][256]
#define N_W1   (H2 * HID)            // 131072
#define OFF_W2 (OFF_W1 + N_W1)       // 229376  w2[512][512]
#define N_W2   (H2 * H2)             // 262144
#define OFF_W3 (OFF_W2 + N_W2)       // 491520  w3[512][512]
#define OFF_W4 (OFF_W3 + N_W2)       // 753664  w4[1024][512]
#define N_W4   (H4 * H2)             // 524288
#define N_TOTAL (OFF_W4 + N_W4)      // 1277952 elements (~2.44 MB bf16)

// ---------------- weight bf16 prep ----------------
__global__ void prep_kernel(const float* __restrict__ fc, const float* __restrict__ w1,
                            const float* __restrict__ w2, const float* __restrict__ w3,
                            const float* __restrict__ w4, __bf16* __restrict__ ws) {
  int idx = blockIdx.x * blockDim.x + threadIdx.x;
  if (idx >= N_TOTAL) return;
  float v;
  if (idx < OFF_W1) {
    // fcW[o][k], k = s*192 + i*64 + g  <-  fc[s][o][i][g], fc shape (2,256,3,64)
    int o = idx / K1, r = idx % K1;
    int s = r / 192, rem = r % 192, i = rem / GRIDW, g = rem % GRIDW;
    v = fc[((s * HID + o) * 3 + i) * GRIDW + g];
  } else if (idx < OFF_W3) {
    v = (idx < OFF_W2) ? w1[idx - OFF_W1] : w2[idx - OFF_W2];
  } else {
    v = (idx < OFF_W4) ? w3[idx - OFF_W3] : w4[idx - OFF_W4];
  }
  ws[idx] = (__bf16)v;
}

// ---------------- fused INR kernel ----------------
// LDS act tiles: [64 points][512 ch] bf16, row stride 1024 B.
// XOR swizzle byte ^= ((n&7)<<4) at 16B granularity (T2) to break the
// stride-1024B bank conflict on ds_read_b128 across 16 rows.

// actfn(z) = (z + tanh(30 z)) * sigmoid(z), via v_exp_f32 / v_rcp_f32.
// tanh(x) = 1 - 2/(e^{2x}+1): exp2->inf gives rcp->0 -> +1; exp2->0 gives -1.
__device__ __forceinline__ float actfn(float z) {
  const float L2E = 1.4426950408889634f;
  float t2 = __builtin_amdgcn_exp2f((2.0f * OMEGA * L2E) * z);
  float th = 1.0f - 2.0f * __builtin_amdgcn_rcpf(t2 + 1.0f);
  float se = __builtin_amdgcn_exp2f(-L2E * z);
  float sg = __builtin_amdgcn_rcpf(1.0f + se);
  return (z + th) * sg;
}

__device__ __forceinline__ void store_act4(unsigned char* sY, int n, int o0,
                                           float a0, float a1, float a2, float a3) {
  b16x4 h;
  h[0] = (__bf16)a0; h[1] = (__bf16)a1; h[2] = (__bf16)a2; h[3] = (__bf16)a3;
  *(b16x4*)(sY + n * 1024 + ((o0 * 2) ^ ((n & 7) << 4))) = h;
}

// C[n, o_base + 0..16*OT) for n in 0..63:  D = W . X^T via mfma(Wfrag, Xfrag)
// D layout: row = o = (lane>>4)*4 + reg (+16*ot), col = n = lane&15 (+16*nt)
// 1-deep software pipeline: ks+1 fragments load while ks MFMAs issue.
template <int K, int OT>
__device__ __forceinline__ void gemm_kloop(const unsigned char* sX, const __bf16* __restrict__ W,
                                           int lane, int o_base, f32x4 (&acc)[OT][4]) {
  const int l15 = lane & 15, lh = lane >> 4;
  constexpr int NK = K / 32;
  b16x8 xf[4], wf[OT];

#pragma unroll
  for (int nt = 0; nt < 4; ++nt) {
    int n = nt * 16 + l15;
    xf[nt] = *(const b16x8*)(sX + n * 1024 + ((lh << 4) ^ ((n & 7) << 4)));
  }
#pragma unroll
  for (int ot = 0; ot < OT; ++ot) {
    int o = o_base + ot * 16 + l15;
    wf[ot] = *(const b16x8*)(W + (size_t)o * K + (lh << 3));
  }

#pragma unroll
  for (int ks = 0; ks < NK; ++ks) {
    b16x8 xn[4], wn[OT];
    if (ks + 1 < NK) {
#pragma unroll
      for (int ot = 0; ot < OT; ++ot) {
        int o = o_base + ot * 16 + l15;
        wn[ot] = *(const b16x8*)(W + (size_t)o * K + (ks + 1) * 32 + (lh << 3));
      }
#pragma unroll
      for (int nt = 0; nt < 4; ++nt) {
        int n = nt * 16 + l15;
        int kb = (ks + 1) * 64 + (lh << 4);
        xn[nt] = *(const b16x8*)(sX + n * 1024 + (kb ^ ((n & 7) << 4)));
      }
    }
#pragma unroll
    for (int ot = 0; ot < OT; ++ot)
#pragma unroll
      for (int nt = 0; nt < 4; ++nt)
        acc[ot][nt] = __builtin_amdgcn_mfma_f32_16x16x32_bf16(wf[ot], xf[nt], acc[ot][nt], 0, 0, 0);
#pragma unroll
    for (int nt = 0; nt < 4; ++nt) xf[nt] = xn[nt];
#pragma unroll
    for (int ot = 0; ot < OT; ++ot) wf[ot] = wn[ot];
  }
}

// one sine layer: read sX (K ch), write sY (512 ch), M = 512, 8 waves * OT=4
template <int K>
__device__ __forceinline__ void sine_layer(const unsigned char* sX, unsigned char* sY,
                                           const __bf16* __restrict__ W,
                                           const float* __restrict__ bias, int lane, int wid) {
  f32x4 acc[4][4] = {};
  const int o_base = wid * 64;
  gemm_kloop<K, 4>(sX, W, lane, o_base, acc);
  const int l15 = lane & 15, lh = lane >> 4;
#pragma unroll
  for (int ot = 0; ot < 4; ++ot) {
    int o0 = o_base + ot * 16 + (lh << 2);
    f32x4 bia = *(const f32x4*)(bias + o0);
#pragma unroll
    for (int nt = 0; nt < 4; ++nt) {
      int n = nt * 16 + l15;
      store_act4(sY, n, o0,
                 actfn(acc[ot][nt][0] + bia[0]), actfn(acc[ot][nt][1] + bia[1]),
                 actfn(acc[ot][nt][2] + bia[2]), actfn(acc[ot][nt][3] + bia[3]));
    }
  }
}

__global__ __launch_bounds__(512, 2) void fkan_inr_kernel(
    const float* __restrict__ coords, const float* __restrict__ fkan_bias,
    const float* __restrict__ ln_g, const float* __restrict__ ln_b,
    const float* __restrict__ b1, const float* __restrict__ b2,
    const float* __restrict__ b3, const float* __restrict__ b4,
    const float* __restrict__ wout, const float* __restrict__ bout,
    const __bf16* __restrict__ ws, float* __restrict__ out) {
  __shared__ __align__(16) unsigned char sA[TILE * 1024];
  __shared__ __align__(16) unsigned char sB[TILE * 1024];
  __shared__ float sSum[TILE], sSqs[TILE];
  __shared__ float sOutF[TILE][4];

  const int tid = threadIdx.x;
  const int lane = tid & 63, wid = tid >> 6;
  const int l15 = lane & 15, lh = lane >> 4;
  const int base_n = blockIdx.x * TILE;

  // ---- Phase F: fourier features -> sA[n][k], k<384 ; zero LN stats
  if (tid < TILE) { sSum[tid] = 0.f; sSqs[tid] = 0.f; }
#pragma unroll
  for (int p = 0; p < 3; ++p) {
    int id = tid + p * 512;               // 0..1535 = (n, i, gchunk of 8)
    int n = id / 24, rem = id % 24, i = rem >> 3, g0 = (rem & 7) * 8;
    float c = coords[(base_n + n) * 3 + i];
    b16x8 cv, sv;
#pragma unroll
    for (int j = 0; j < 8; ++j) {
      float ang = c * (float)(g0 + j + 1);
      float s, co;
      sincosf(ang, &s, &co);
      cv[j] = (__bf16)co;
      sv[j] = (__bf16)s;
    }
    int kc = (i * GRIDW + g0) * 2;
    *(b16x8*)(sA + n * 1024 + (kc ^ ((n & 7) << 4))) = cv;
    int ks2 = (192 + i * GRIDW + g0) * 2;
    *(b16x8*)(sA + n * 1024 + (ks2 ^ ((n & 7) << 4))) = sv;
  }
  __syncthreads();

  // ---- GEMM1 (384 -> 256) + fkan_bias + LayerNorm -> sB
  {
    f32x4 acc[2][4] = {};
    const int o_base = wid * 32;
    gemm_kloop<K1, 2>(sA, ws + OFF_FC, lane, o_base, acc);
#pragma unroll
    for (int ot = 0; ot < 2; ++ot) {
      int o0 = o_base + ot * 16 + (lh << 2);
      f32x4 bia = *(const f32x4*)(fkan_bias + o0);
#pragma unroll
      for (int nt = 0; nt < 4; ++nt) acc[ot][nt] += bia;
    }
#pragma unroll
    for (int nt = 0; nt < 4; ++nt) {
      float s = 0.f, q = 0.f;
#pragma unroll
      for (int ot = 0; ot < 2; ++ot)
#pragma unroll
        for (int r = 0; r < 4; ++r) { float z = acc[ot][nt][r]; s += z; q += z * z; }
      s += __shfl_xor(s, 16); q += __shfl_xor(q, 16);
      s += __shfl_xor(s, 32); q += __shfl_xor(q, 32);
      if (lane < 16) {
        atomicAdd(&sSum[nt * 16 + lane], s);
        atomicAdd(&sSqs[nt * 16 + lane], q);
      }
    }
    __syncthreads();
#pragma unroll
    for (int nt = 0; nt < 4; ++nt) {
      int n = nt * 16 + l15;
      float mu = sSum[n] * (1.f / HID);
      float var = sSqs[n] * (1.f / HID) - mu * mu;
      float rs = rsqrtf(var + LN_EPS);
#pragma unroll
      for (int ot = 0; ot < 2; ++ot) {
        int o0 = o_base + ot * 16 + (lh << 2);
        f32x4 g4 = *(const f32x4*)(ln_g + o0);
        f32x4 bb = *(const f32x4*)(ln_b + o0);
        store_act4(sB, n, o0,
                   (acc[ot][nt][0] - mu) * rs * g4[0] + bb[0],
                   (acc[ot][nt][1] - mu) * rs * g4[1] + bb[1],
                   (acc[ot][nt][2] - mu) * rs * g4[2] + bb[2],
                   (acc[ot][nt][3] - mu) * rs * g4[3] + bb[3]);
      }
    }
    __syncthreads();
  }

  // ---- sine layers 1..3
  sine_layer<HID>(sB, sA, ws + OFF_W1, b1, lane, wid);
  __syncthreads();
  sine_layer<H2>(sA, sB, ws + OFF_W2, b2, lane, wid);
  __syncthreads();
  sine_layer<H2>(sB, sA, ws + OFF_W3, b3, lane, wid);
  if (tid < TILE) { sOutF[tid][0] = 0.f; sOutF[tid][1] = 0.f; sOutF[tid][2] = 0.f; sOutF[tid][3] = 0.f; }
  __syncthreads();

  // ---- layer 4 (512 -> 1024) fused with output projection (1024 -> 3)
  {
    float pj[4][3] = {};
#pragma unroll
    for (int pass = 0; pass < 2; ++pass) {
      f32x4 acc[4][4] = {};
      int o_base = wid * 128 + pass * 64;
      gemm_kloop<H2, 4>(sA, ws + OFF_W4, lane, o_base, acc);
#pragma unroll
      for (int ot = 0; ot < 4; ++ot) {
        int o0 = o_base + ot * 16 + (lh << 2);
        f32x4 bia = *(const f32x4*)(b4 + o0);
        f32x4 wo0 = *(const f32x4*)(wout + 0 * H4 + o0);
        f32x4 wo1 = *(const f32x4*)(wout + 1 * H4 + o0);
        f32x4 wo2 = *(const f32x4*)(wout + 2 * H4 + o0);
#pragma unroll
        for (int nt = 0; nt < 4; ++nt) {
          float a0 = actfn(acc[ot][nt][0] + bia[0]);
          float a1 = actfn(acc[ot][nt][1] + bia[1]);
          float a2 = actfn(acc[ot][nt][2] + bia[2]);
          float a3 = actfn(acc[ot][nt][3] + bia[3]);
          pj[nt][0] += a0 * wo0[0] + a1 * wo0[1] + a2 * wo0[2] + a3 * wo0[3];
          pj[nt][1] += a0 * wo1[0] + a1 * wo1[1] + a2 * wo1[2] + a3 * wo1[3];
          pj[nt][2] += a0 * wo2[0] + a1 * wo2[1] + a2 * wo2[2] + a3 * wo2[3];
        }
      }
    }
#pragma unroll
    for (int nt = 0; nt < 4; ++nt)
#pragma unroll
      for (int j = 0; j < 3; ++j) {
        float r = pj[nt][j];
        r += __shfl_xor(r, 16);
        r += __shfl_xor(r, 32);
        if (lane < 16) atomicAdd(&sOutF[nt * 16 + lane][j], r);
      }
    __syncthreads();
    if (tid < TILE * 3) {
      int n = tid / 3, j = tid % 3;
      out[(base_n + n) * 3 + j] = sOutF[n][j] + bout[j];
    }
  }
}

extern "C" void kernel_launch(void* const* d_in, const int* in_sizes, int n_in,
                              void* d_out, int out_size, void* d_ws, size_t ws_size,
                              hipStream_t stream) {
  const float* coords    = (const float*)d_in[0];
  const float* fc        = (const float*)d_in[1];
  const float* fkan_bias = (const float*)d_in[2];
  const float* ln_g      = (const float*)d_in[3];
  const float* ln_b      = (const float*)d_in[4];
  const float* w1        = (const float*)d_in[5];
  const float* b1        = (const float*)d_in[6];
  const float* w2        = (const float*)d_in[7];
  const float* b2        = (const float*)d_in[8];
  const float* w3        = (const float*)d_in[9];
  const float* b3        = (const float*)d_in[10];
  const float* w4        = (const float*)d_in[11];
  const float* b4        = (const float*)d_in[12];
  const float* wout      = (const float*)d_in[13];
  const float* bout      = (const float*)d_in[14];
  float* out = (float*)d_out;
  __bf16* ws = (__bf16*)d_ws;

  prep_kernel<<<(N_TOTAL + 255) / 256, 256, 0, stream>>>(fc, w1, w2, w3, w4, ws);
  fkan_inr_kernel<<<N_PTS / TILE, 512, 0, stream>>>(coords, fkan_bias, ln_g, ln_b,
                                                    b1, b2, b3, b4, wout, bout, ws, out);
}

// Round 3
// 779.556 us; speedup vs baseline: 1.8017x; 1.1028x over previous
//
#include <hip/hip_runtime.h>
#include <math.h>

#define N_PTS 131072
#define HID 256
#define H2 512
#define H4 1024
#define GRIDW 64
#define K1 384          // 2 * 3 * 64 fourier features
#define TILE 64         // points per block
#define LN_EPS 1e-5f
#define OMEGA 30.0f

typedef __bf16 b16x8 __attribute__((ext_vector_type(8)));
typedef __bf16 b16x4 __attribute__((ext_vector_type(4)));
typedef float f32x4 __attribute__((ext_vector_type(4)));

// bf16 weight workspace layout (element offsets)
#define OFF_FC 0
#define N_FC   (HID * K1)            // 98304   fcW[256][384]
#define OFF_W1 (OFF_FC + N_FC)       // 98304   w1[512][256]
#define N_W1   (H2 * HID)            // 131072
#define OFF_W2 (OFF_W1 + N_W1)       // 229376  w2[512][512]
#define N_W2   (H2 * H2)             // 262144
#define OFF_W3 (OFF_W2 + N_W2)       // 491520  w3[512][512]
#define OFF_W4 (OFF_W3 + N_W2)       // 753664  w4[1024][512]
#define N_W4   (H4 * H2)             // 524288
#define N_TOTAL (OFF_W4 + N_W4)      // 1277952 elements (~2.44 MB bf16)

// ---------------- weight bf16 prep ----------------
__global__ void prep_kernel(const float* __restrict__ fc, const float* __restrict__ w1,
                            const float* __restrict__ w2, const float* __restrict__ w3,
                            const float* __restrict__ w4, __bf16* __restrict__ ws) {
  int idx = blockIdx.x * blockDim.x + threadIdx.x;
  if (idx >= N_TOTAL) return;
  float v;
  if (idx < OFF_W1) {
    // fcW[o][k], k = s*192 + i*64 + g  <-  fc[s][o][i][g], fc shape (2,256,3,64)
    int o = idx / K1, r = idx % K1;
    int s = r / 192, rem = r % 192, i = rem / GRIDW, g = rem % GRIDW;
    v = fc[((s * HID + o) * 3 + i) * GRIDW + g];
  } else if (idx < OFF_W3) {
    v = (idx < OFF_W2) ? w1[idx - OFF_W1] : w2[idx - OFF_W2];
  } else {
    v = (idx < OFF_W4) ? w3[idx - OFF_W3] : w4[idx - OFF_W4];
  }
  ws[idx] = (__bf16)v;
}

// ---------------- fused INR kernel ----------------
// LDS act tiles: [64 points][512 ch] bf16, row stride 1024 B.
// XOR swizzle byte ^= ((n&7)<<4) at 16B granularity (T2) to break the
// stride-1024B bank conflict on ds_read_b128 across 16 rows.

// actfn(z) = (z + tanh(30 z)) * sigmoid(z), via v_exp_f32 / v_rcp_f32.
// tanh(x) = 1 - 2/(e^{2x}+1): exp2->inf gives rcp->0 -> +1; exp2->0 gives -1.
__device__ __forceinline__ float actfn(float z) {
  const float L2E = 1.4426950408889634f;
  float t2 = __builtin_amdgcn_exp2f((2.0f * OMEGA * L2E) * z);
  float th = 1.0f - 2.0f * __builtin_amdgcn_rcpf(t2 + 1.0f);
  float se = __builtin_amdgcn_exp2f(-L2E * z);
  float sg = __builtin_amdgcn_rcpf(1.0f + se);
  return (z + th) * sg;
}

// HW sincos: v_sin/v_cos take REVOLUTIONS. ang <= 64 rad = 10.2 rev, fract first.
__device__ __forceinline__ void fast_sincos(float ang, float* s, float* c) {
  const float INV2PI = 0.15915493667125702f;
  float r = __builtin_amdgcn_fractf(ang * INV2PI);
  *s = __builtin_amdgcn_sinf(r);
  *c = __builtin_amdgcn_cosf(r);
}

__device__ __forceinline__ void store_act4(unsigned char* sY, int n, int o0,
                                           float a0, float a1, float a2, float a3) {
  b16x4 h;
  h[0] = (__bf16)a0; h[1] = (__bf16)a1; h[2] = (__bf16)a2; h[3] = (__bf16)a3;
  *(b16x4*)(sY + n * 1024 + ((o0 * 2) ^ ((n & 7) << 4))) = h;
}

// C[n, o_base + 0..16*OT) for n in 0..63:  D = W . X^T via mfma(Wfrag, Xfrag)
// D layout: row = o = (lane>>4)*4 + reg (+16*ot), col = n = lane&15 (+16*nt)
// 1-deep software pipeline, unroll 2 (NOT full: full unroll hoists loads and spills).
template <int K, int OT>
__device__ __forceinline__ void gemm_kloop(const unsigned char* sX, const __bf16* __restrict__ W,
                                           int lane, int o_base, f32x4 (&acc)[OT][4]) {
  const int l15 = lane & 15, lh = lane >> 4;
  constexpr int NK = K / 32;
  b16x8 xf[4], wf[OT];

#pragma unroll
  for (int nt = 0; nt < 4; ++nt) {
    int n = nt * 16 + l15;
    xf[nt] = *(const b16x8*)(sX + n * 1024 + ((lh << 4) ^ ((n & 7) << 4)));
  }
#pragma unroll
  for (int ot = 0; ot < OT; ++ot) {
    int o = o_base + ot * 16 + l15;
    wf[ot] = *(const b16x8*)(W + (size_t)o * K + (lh << 3));
  }

#pragma unroll 2
  for (int ks = 0; ks < NK; ++ks) {
    b16x8 xn[4], wn[OT];
    if (ks + 1 < NK) {
#pragma unroll
      for (int ot = 0; ot < OT; ++ot) {
        int o = o_base + ot * 16 + l15;
        wn[ot] = *(const b16x8*)(W + (size_t)o * K + (ks + 1) * 32 + (lh << 3));
      }
#pragma unroll
      for (int nt = 0; nt < 4; ++nt) {
        int n = nt * 16 + l15;
        int kb = (ks + 1) * 64 + (lh << 4);
        xn[nt] = *(const b16x8*)(sX + n * 1024 + (kb ^ ((n & 7) << 4)));
      }
    }
#pragma unroll
    for (int ot = 0; ot < OT; ++ot)
#pragma unroll
      for (int nt = 0; nt < 4; ++nt)
        acc[ot][nt] = __builtin_amdgcn_mfma_f32_16x16x32_bf16(wf[ot], xf[nt], acc[ot][nt], 0, 0, 0);
#pragma unroll
    for (int nt = 0; nt < 4; ++nt) xf[nt] = xn[nt];
#pragma unroll
    for (int ot = 0; ot < OT; ++ot) wf[ot] = wn[ot];
  }
}

// one sine layer: read sX (K ch), write sY (512 ch), M = 512, 8 waves * OT=4
template <int K>
__device__ __forceinline__ void sine_layer(const unsigned char* sX, unsigned char* sY,
                                           const __bf16* __restrict__ W,
                                           const float* __restrict__ bias, int lane, int wid) {
  f32x4 acc[4][4] = {};
  const int o_base = wid * 64;
  gemm_kloop<K, 4>(sX, W, lane, o_base, acc);
  const int l15 = lane & 15, lh = lane >> 4;
#pragma unroll
  for (int ot = 0; ot < 4; ++ot) {
    int o0 = o_base + ot * 16 + (lh << 2);
    f32x4 bia = *(const f32x4*)(bias + o0);
#pragma unroll
    for (int nt = 0; nt < 4; ++nt) {
      int n = nt * 16 + l15;
      store_act4(sY, n, o0,
                 actfn(acc[ot][nt][0] + bia[0]), actfn(acc[ot][nt][1] + bia[1]),
                 actfn(acc[ot][nt][2] + bia[2]), actfn(acc[ot][nt][3] + bia[3]));
    }
  }
}

__global__ __launch_bounds__(512, 2) void fkan_inr_kernel(
    const float* __restrict__ coords, const float* __restrict__ fkan_bias,
    const float* __restrict__ ln_g, const float* __restrict__ ln_b,
    const float* __restrict__ b1, const float* __restrict__ b2,
    const float* __restrict__ b3, const float* __restrict__ b4,
    const float* __restrict__ wout, const float* __restrict__ bout,
    const __bf16* __restrict__ ws, float* __restrict__ out) {
  __shared__ __align__(16) unsigned char sA[TILE * 1024];
  __shared__ __align__(16) unsigned char sB[TILE * 1024];
  __shared__ float sSum[TILE], sSqs[TILE];
  __shared__ float sOutF[TILE][4];

  const int tid = threadIdx.x;
  const int lane = tid & 63, wid = tid >> 6;
  const int l15 = lane & 15, lh = lane >> 4;
  const int base_n = blockIdx.x * TILE;

  // ---- Phase F: fourier features -> sA[n][k], k<384 ; zero LN stats
  if (tid < TILE) { sSum[tid] = 0.f; sSqs[tid] = 0.f; }
#pragma unroll
  for (int p = 0; p < 3; ++p) {
    int id = tid + p * 512;               // 0..1535 = (n, i, gchunk of 8)
    int n = id / 24, rem = id % 24, i = rem >> 3, g0 = (rem & 7) * 8;
    float c = coords[(base_n + n) * 3 + i];
    b16x8 cv, sv;
#pragma unroll
    for (int j = 0; j < 8; ++j) {
      float ang = c * (float)(g0 + j + 1);
      float s, co;
      fast_sincos(ang, &s, &co);
      cv[j] = (__bf16)co;
      sv[j] = (__bf16)s;
    }
    int kc = (i * GRIDW + g0) * 2;
    *(b16x8*)(sA + n * 1024 + (kc ^ ((n & 7) << 4))) = cv;
    int ks2 = (192 + i * GRIDW + g0) * 2;
    *(b16x8*)(sA + n * 1024 + (ks2 ^ ((n & 7) << 4))) = sv;
  }
  __syncthreads();

  // ---- GEMM1 (384 -> 256) + fkan_bias + LayerNorm -> sB
  {
    f32x4 acc[2][4] = {};
    const int o_base = wid * 32;
    gemm_kloop<K1, 2>(sA, ws + OFF_FC, lane, o_base, acc);
#pragma unroll
    for (int ot = 0; ot < 2; ++ot) {
      int o0 = o_base + ot * 16 + (lh << 2);
      f32x4 bia = *(const f32x4*)(fkan_bias + o0);
#pragma unroll
      for (int nt = 0; nt < 4; ++nt) acc[ot][nt] += bia;
    }
#pragma unroll
    for (int nt = 0; nt < 4; ++nt) {
      float s = 0.f, q = 0.f;
#pragma unroll
      for (int ot = 0; ot < 2; ++ot)
#pragma unroll
        for (int r = 0; r < 4; ++r) { float z = acc[ot][nt][r]; s += z; q += z * z; }
      s += __shfl_xor(s, 16); q += __shfl_xor(q, 16);
      s += __shfl_xor(s, 32); q += __shfl_xor(q, 32);
      if (lane < 16) {
        atomicAdd(&sSum[nt * 16 + lane], s);
        atomicAdd(&sSqs[nt * 16 + lane], q);
      }
    }
    __syncthreads();
#pragma unroll
    for (int nt = 0; nt < 4; ++nt) {
      int n = nt * 16 + l15;
      float mu = sSum[n] * (1.f / HID);
      float var = sSqs[n] * (1.f / HID) - mu * mu;
      float rs = rsqrtf(var + LN_EPS);
#pragma unroll
      for (int ot = 0; ot < 2; ++ot) {
        int o0 = o_base + ot * 16 + (lh << 2);
        f32x4 g4 = *(const f32x4*)(ln_g + o0);
        f32x4 bb = *(const f32x4*)(ln_b + o0);
        store_act4(sB, n, o0,
                   (acc[ot][nt][0] - mu) * rs * g4[0] + bb[0],
                   (acc[ot][nt][1] - mu) * rs * g4[1] + bb[1],
                   (acc[ot][nt][2] - mu) * rs * g4[2] + bb[2],
                   (acc[ot][nt][3] - mu) * rs * g4[3] + bb[3]);
      }
    }
    __syncthreads();
  }

  // ---- sine layers 1..3
  sine_layer<HID>(sB, sA, ws + OFF_W1, b1, lane, wid);
  __syncthreads();
  sine_layer<H2>(sA, sB, ws + OFF_W2, b2, lane, wid);
  __syncthreads();
  sine_layer<H2>(sB, sA, ws + OFF_W3, b3, lane, wid);
  if (tid < TILE) { sOutF[tid][0] = 0.f; sOutF[tid][1] = 0.f; sOutF[tid][2] = 0.f; sOutF[tid][3] = 0.f; }
  __syncthreads();

  // ---- layer 4 (512 -> 1024) fused with output projection (1024 -> 3)
  {
    float pj[4][3] = {};
#pragma unroll
    for (int pass = 0; pass < 2; ++pass) {
      f32x4 acc[4][4] = {};
      int o_base = wid * 128 + pass * 64;
      gemm_kloop<H2, 4>(sA, ws + OFF_W4, lane, o_base, acc);
#pragma unroll
      for (int ot = 0; ot < 4; ++ot) {
        int o0 = o_base + ot * 16 + (lh << 2);
        f32x4 bia = *(const f32x4*)(b4 + o0);
        f32x4 wo0 = *(const f32x4*)(wout + 0 * H4 + o0);
        f32x4 wo1 = *(const f32x4*)(wout + 1 * H4 + o0);
        f32x4 wo2 = *(const f32x4*)(wout + 2 * H4 + o0);
#pragma unroll
        for (int nt = 0; nt < 4; ++nt) {
          float a0 = actfn(acc[ot][nt][0] + bia[0]);
          float a1 = actfn(acc[ot][nt][1] + bia[1]);
          float a2 = actfn(acc[ot][nt][2] + bia[2]);
          float a3 = actfn(acc[ot][nt][3] + bia[3]);
          pj[nt][0] += a0 * wo0[0] + a1 * wo0[1] + a2 * wo0[2] + a3 * wo0[3];
          pj[nt][1] += a0 * wo1[0] + a1 * wo1[1] + a2 * wo1[2] + a3 * wo1[3];
          pj[nt][2] += a0 * wo2[0] + a1 * wo2[1] + a2 * wo2[2] + a3 * wo2[3];
        }
      }
    }
#pragma unroll
    for (int nt = 0; nt < 4; ++nt)
#pragma unroll
      for (int j = 0; j < 3; ++j) {
        float r = pj[nt][j];
        r += __shfl_xor(r, 16);
        r += __shfl_xor(r, 32);
        if (lane < 16) atomicAdd(&sOutF[nt * 16 + lane][j], r);
      }
    __syncthreads();
    if (tid < TILE * 3) {
      int n = tid / 3, j = tid % 3;
      out[(base_n + n) * 3 + j] = sOutF[n][j] + bout[j];
    }
  }
}

extern "C" void kernel_launch(void* const* d_in, const int* in_sizes, int n_in,
                              void* d_out, int out_size, void* d_ws, size_t ws_size,
                              hipStream_t stream) {
  const float* coords    = (const float*)d_in[0];
  const float* fc        = (const float*)d_in[1];
  const float* fkan_bias = (const float*)d_in[2];
  const float* ln_g      = (const float*)d_in[3];
  const float* ln_b      = (const float*)d_in[4];
  const float* w1        = (const float*)d_in[5];
  const float* b1        = (const float*)d_in[6];
  const float* w2        = (const float*)d_in[7];
  const float* b2        = (const float*)d_in[8];
  const float* w3        = (const float*)d_in[9];
  const float* b3        = (const float*)d_in[10];
  const float* w4        = (const float*)d_in[11];
  const float* b4        = (const float*)d_in[12];
  const float* wout      = (const float*)d_in[13];
  const float* bout      = (const float*)d_in[14];
  float* out = (float*)d_out;
  __bf16* ws = (__bf16*)d_ws;

  prep_kernel<<<(N_TOTAL + 255) / 256, 256, 0, stream>>>(fc, w1, w2, w3, w4, ws);
  fkan_inr_kernel<<<N_PTS / TILE, 512, 0, stream>>>(coords, fkan_bias, ln_g, ln_b,
                                                    b1, b2, b3, b4, wout, bout, ws, out);
}

// Round 4
// 651.812 us; speedup vs baseline: 2.1548x; 1.1960x over previous
//
#include <hip/hip_runtime.h>
#include <math.h>

#define N_PTS 131072
#define HID 256
#define H2 512
#define H4 1024
#define GRIDW 64
#define K1 384          // 2 * 3 * 64 fourier features
#define TILE 64         // points per block
#define LN_EPS 1e-5f
#define OMEGA 30.0f

typedef __bf16 b16x8 __attribute__((ext_vector_type(8)));
typedef __bf16 b16x4 __attribute__((ext_vector_type(4)));
typedef float f32x4 __attribute__((ext_vector_type(4)));

// bf16 weight workspace layout (element offsets)
#define OFF_FC 0
#define N_FC   (HID * K1)            // 98304   fcW[256][384]
#define OFF_W1 (OFF_FC + N_FC)       // 98304   w1[512][256]
#define N_W1   (H2 * HID)            // 131072
#define OFF_W2 (OFF_W1 + N_W1)       // 229376  w2[512][512]
#define N_W2   (H2 * H2)             // 262144
#define OFF_W3 (OFF_W2 + N_W2)       // 491520  w3[512][512]
#define OFF_W4 (OFF_W3 + N_W2)       // 753664  w4[1024][512]
#define N_W4   (H4 * H2)             // 524288
#define N_TOTAL (OFF_W4 + N_W4)      // 1277952 elements (~2.44 MB bf16)

// ---------------- weight bf16 prep ----------------
__global__ void prep_kernel(const float* __restrict__ fc, const float* __restrict__ w1,
                            const float* __restrict__ w2, const float* __restrict__ w3,
                            const float* __restrict__ w4, __bf16* __restrict__ ws) {
  int idx = blockIdx.x * blockDim.x + threadIdx.x;
  if (idx >= N_TOTAL) return;
  float v;
  if (idx < OFF_W1) {
    // fcW[o][k], k = s*192 + i*64 + g  <-  fc[s][o][i][g], fc shape (2,256,3,64)
    int o = idx / K1, r = idx % K1;
    int s = r / 192, rem = r % 192, i = rem / GRIDW, g = rem % GRIDW;
    v = fc[((s * HID + o) * 3 + i) * GRIDW + g];
  } else if (idx < OFF_W3) {
    v = (idx < OFF_W2) ? w1[idx - OFF_W1] : w2[idx - OFF_W2];
  } else {
    v = (idx < OFF_W4) ? w3[idx - OFF_W3] : w4[idx - OFF_W4];
  }
  ws[idx] = (__bf16)v;
}

// ---------------- fused INR kernel ----------------
// Single in-place LDS act tile: [64 points][<=512 ch] bf16, row stride 1024 B.
// XOR swizzle byte ^= ((n&7)<<4) at 16B granularity (T2) breaks the
// stride-1024B bank conflict on ds_read_b128 across 16 rows.
// Per layer: gemm (reads tile) -> activate into regs -> barrier -> write back
// to the SAME tile -> barrier.  66 KB LDS -> 2 blocks/CU, 16 waves/CU.

// actfn(z) = (z + tanh(30 z)) * sigmoid(z), via v_exp_f32 / v_rcp_f32.
// tanh(x) = 1 - 2/(e^{2x}+1): exp2->inf gives rcp->0 -> +1; exp2->0 gives -1.
__device__ __forceinline__ float actfn(float z) {
  const float L2E = 1.4426950408889634f;
  float t2 = __builtin_amdgcn_exp2f((2.0f * OMEGA * L2E) * z);
  float th = 1.0f - 2.0f * __builtin_amdgcn_rcpf(t2 + 1.0f);
  float se = __builtin_amdgcn_exp2f(-L2E * z);
  float sg = __builtin_amdgcn_rcpf(1.0f + se);
  return (z + th) * sg;
}

// HW sincos: v_sin/v_cos take REVOLUTIONS. ang <= 64 rad = 10.2 rev, fract first.
__device__ __forceinline__ void fast_sincos(float ang, float* s, float* c) {
  const float INV2PI = 0.15915493667125702f;
  float r = __builtin_amdgcn_fractf(ang * INV2PI);
  *s = __builtin_amdgcn_sinf(r);
  *c = __builtin_amdgcn_cosf(r);
}

// C[n, o_base + 0..16*OT) for n in 0..63:  D = W . X^T via mfma(Wfrag, Xfrag)
// D layout: row = o = (lane>>4)*4 + reg (+16*ot), col = n = lane&15 (+16*nt)
// No register prefetch (spilled at the 128-reg cap); 4 waves/SIMD TLP hides it.
template <int K, int OT>
__device__ __forceinline__ void gemm_kloop(const unsigned char* sX, const __bf16* __restrict__ W,
                                           int lane, int o_base, f32x4 (&acc)[OT][4]) {
  const int l15 = lane & 15, lh = lane >> 4;
  constexpr int NK = K / 32;
#pragma unroll 2
  for (int ks = 0; ks < NK; ++ks) {
    b16x8 xf[4];
#pragma unroll
    for (int nt = 0; nt < 4; ++nt) {
      int n = nt * 16 + l15;
      int kb = ks * 64 + (lh << 4);
      xf[nt] = *(const b16x8*)(sX + n * 1024 + (kb ^ ((n & 7) << 4)));
    }
    b16x8 wf[OT];
#pragma unroll
    for (int ot = 0; ot < OT; ++ot) {
      int o = o_base + ot * 16 + l15;
      wf[ot] = *(const b16x8*)(W + (size_t)o * K + ks * 32 + (lh << 3));
    }
#pragma unroll
    for (int ot = 0; ot < OT; ++ot)
#pragma unroll
      for (int nt = 0; nt < 4; ++nt)
        acc[ot][nt] = __builtin_amdgcn_mfma_f32_16x16x32_bf16(wf[ot], xf[nt], acc[ot][nt], 0, 0, 0);
  }
}

// one sine layer IN PLACE: read sAct (K ch), write sAct (512 ch). 8 waves * OT=4.
template <int K>
__device__ __forceinline__ void sine_layer_ip(unsigned char* sAct,
                                              const __bf16* __restrict__ W,
                                              const float* __restrict__ bias, int lane, int wid) {
  f32x4 acc[4][4] = {};
  const int o_base = wid * 64;
  gemm_kloop<K, 4>(sAct, W, lane, o_base, acc);
  const int l15 = lane & 15, lh = lane >> 4;
  b16x4 st[4][4];
#pragma unroll
  for (int ot = 0; ot < 4; ++ot) {
    int o0 = o_base + ot * 16 + (lh << 2);
    f32x4 bia = *(const f32x4*)(bias + o0);
#pragma unroll
    for (int nt = 0; nt < 4; ++nt) {
      st[ot][nt][0] = (__bf16)actfn(acc[ot][nt][0] + bia[0]);
      st[ot][nt][1] = (__bf16)actfn(acc[ot][nt][1] + bia[1]);
      st[ot][nt][2] = (__bf16)actfn(acc[ot][nt][2] + bia[2]);
      st[ot][nt][3] = (__bf16)actfn(acc[ot][nt][3] + bia[3]);
    }
  }
  __syncthreads();  // all waves finished READING sAct
#pragma unroll
  for (int ot = 0; ot < 4; ++ot) {
    int o0 = o_base + ot * 16 + (lh << 2);
#pragma unroll
    for (int nt = 0; nt < 4; ++nt) {
      int n = nt * 16 + l15;
      *(b16x4*)(sAct + n * 1024 + ((o0 * 2) ^ ((n & 7) << 4))) = st[ot][nt];
    }
  }
  __syncthreads();  // writes visible
}

__global__ __launch_bounds__(512, 4) void fkan_inr_kernel(
    const float* __restrict__ coords, const float* __restrict__ fkan_bias,
    const float* __restrict__ ln_g, const float* __restrict__ ln_b,
    const float* __restrict__ b1, const float* __restrict__ b2,
    const float* __restrict__ b3, const float* __restrict__ b4,
    const float* __restrict__ wout, const float* __restrict__ bout,
    const __bf16* __restrict__ ws, float* __restrict__ out) {
  __shared__ __align__(16) unsigned char sAct[TILE * 1024];
  __shared__ float sSum[TILE], sSqs[TILE];
  __shared__ float sOutF[TILE][4];

  const int tid = threadIdx.x;
  const int lane = tid & 63, wid = tid >> 6;
  const int l15 = lane & 15, lh = lane >> 4;
  const int base_n = blockIdx.x * TILE;

  // ---- Phase F: fourier features -> sAct[n][k], k<384 ; zero LN stats + out acc
  if (tid < TILE) {
    sSum[tid] = 0.f; sSqs[tid] = 0.f;
    sOutF[tid][0] = 0.f; sOutF[tid][1] = 0.f; sOutF[tid][2] = 0.f; sOutF[tid][3] = 0.f;
  }
#pragma unroll
  for (int p = 0; p < 3; ++p) {
    int id = tid + p * 512;               // 0..1535 = (n, i, gchunk of 8)
    int n = id / 24, rem = id % 24, i = rem >> 3, g0 = (rem & 7) * 8;
    float c = coords[(base_n + n) * 3 + i];
    b16x8 cv, sv;
#pragma unroll
    for (int j = 0; j < 8; ++j) {
      float ang = c * (float)(g0 + j + 1);
      float s, co;
      fast_sincos(ang, &s, &co);
      cv[j] = (__bf16)co;
      sv[j] = (__bf16)s;
    }
    int kc = (i * GRIDW + g0) * 2;
    *(b16x8*)(sAct + n * 1024 + (kc ^ ((n & 7) << 4))) = cv;
    int ks2 = (192 + i * GRIDW + g0) * 2;
    *(b16x8*)(sAct + n * 1024 + (ks2 ^ ((n & 7) << 4))) = sv;
  }
  __syncthreads();

  // ---- GEMM1 (384 -> 256) + fkan_bias + LayerNorm, in place
  {
    f32x4 acc[2][4] = {};
    const int o_base = wid * 32;
    gemm_kloop<K1, 2>(sAct, ws + OFF_FC, lane, o_base, acc);
#pragma unroll
    for (int ot = 0; ot < 2; ++ot) {
      int o0 = o_base + ot * 16 + (lh << 2);
      f32x4 bia = *(const f32x4*)(fkan_bias + o0);
#pragma unroll
      for (int nt = 0; nt < 4; ++nt) acc[ot][nt] += bia;
    }
#pragma unroll
    for (int nt = 0; nt < 4; ++nt) {
      float s = 0.f, q = 0.f;
#pragma unroll
      for (int ot = 0; ot < 2; ++ot)
#pragma unroll
        for (int r = 0; r < 4; ++r) { float z = acc[ot][nt][r]; s += z; q += z * z; }
      s += __shfl_xor(s, 16); q += __shfl_xor(q, 16);
      s += __shfl_xor(s, 32); q += __shfl_xor(q, 32);
      if (lane < 16) {
        atomicAdd(&sSum[nt * 16 + lane], s);
        atomicAdd(&sSqs[nt * 16 + lane], q);
      }
    }
    __syncthreads();  // stats ready AND all feature reads done
#pragma unroll
    for (int nt = 0; nt < 4; ++nt) {
      int n = nt * 16 + l15;
      float mu = sSum[n] * (1.f / HID);
      float var = sSqs[n] * (1.f / HID) - mu * mu;
      float rs = rsqrtf(var + LN_EPS);
#pragma unroll
      for (int ot = 0; ot < 2; ++ot) {
        int o0 = o_base + ot * 16 + (lh << 2);
        f32x4 g4 = *(const f32x4*)(ln_g + o0);
        f32x4 bb = *(const f32x4*)(ln_b + o0);
        b16x4 h;
        h[0] = (__bf16)((acc[ot][nt][0] - mu) * rs * g4[0] + bb[0]);
        h[1] = (__bf16)((acc[ot][nt][1] - mu) * rs * g4[1] + bb[1]);
        h[2] = (__bf16)((acc[ot][nt][2] - mu) * rs * g4[2] + bb[2]);
        h[3] = (__bf16)((acc[ot][nt][3] - mu) * rs * g4[3] + bb[3]);
        *(b16x4*)(sAct + n * 1024 + ((o0 * 2) ^ ((n & 7) << 4))) = h;
      }
    }
    __syncthreads();
  }

  // ---- sine layers 1..3 (in place)
  sine_layer_ip<HID>(sAct, ws + OFF_W1, b1, lane, wid);
  sine_layer_ip<H2>(sAct, ws + OFF_W2, b2, lane, wid);
  sine_layer_ip<H2>(sAct, ws + OFF_W3, b3, lane, wid);

  // ---- layer 4 (512 -> 1024) fused with output projection (1024 -> 3)
  {
#pragma unroll
    for (int pass = 0; pass < 2; ++pass) {
      f32x4 acc[4][4] = {};
      int o_base = pass * 512 + wid * 64;
      gemm_kloop<H2, 4>(sAct, ws + OFF_W4, lane, o_base, acc);
      float pj[4][3] = {};
#pragma unroll
      for (int ot = 0; ot < 4; ++ot) {
        int o0 = o_base + ot * 16 + (lh << 2);
        f32x4 bia = *(const f32x4*)(b4 + o0);
        f32x4 wo0 = *(const f32x4*)(wout + 0 * H4 + o0);
        f32x4 wo1 = *(const f32x4*)(wout + 1 * H4 + o0);
        f32x4 wo2 = *(const f32x4*)(wout + 2 * H4 + o0);
#pragma unroll
        for (int nt = 0; nt < 4; ++nt) {
          float a0 = actfn(acc[ot][nt][0] + bia[0]);
          float a1 = actfn(acc[ot][nt][1] + bia[1]);
          float a2 = actfn(acc[ot][nt][2] + bia[2]);
          float a3 = actfn(acc[ot][nt][3] + bia[3]);
          pj[nt][0] += a0 * wo0[0] + a1 * wo0[1] + a2 * wo0[2] + a3 * wo0[3];
          pj[nt][1] += a0 * wo1[0] + a1 * wo1[1] + a2 * wo1[2] + a3 * wo1[3];
          pj[nt][2] += a0 * wo2[0] + a1 * wo2[1] + a2 * wo2[2] + a3 * wo2[3];
        }
      }
#pragma unroll
      for (int nt = 0; nt < 4; ++nt)
#pragma unroll
        for (int j = 0; j < 3; ++j) {
          float r = pj[nt][j];
          r += __shfl_xor(r, 16);
          r += __shfl_xor(r, 32);
          if (lane < 16) atomicAdd(&sOutF[nt * 16 + lane][j], r);
        }
    }
    __syncthreads();
    if (tid < TILE * 3) {
      int n = tid / 3, j = tid % 3;
      out[(base_n + n) * 3 + j] = sOutF[n][j] + bout[j];
    }
  }
}

extern "C" void kernel_launch(void* const* d_in, const int* in_sizes, int n_in,
                              void* d_out, int out_size, void* d_ws, size_t ws_size,
                              hipStream_t stream) {
  const float* coords    = (const float*)d_in[0];
  const float* fc        = (const float*)d_in[1];
  const float* fkan_bias = (const float*)d_in[2];
  const float* ln_g      = (const float*)d_in[3];
  const float* ln_b      = (const float*)d_in[4];
  const float* w1        = (const float*)d_in[5];
  const float* b1        = (const float*)d_in[6];
  const float* w2        = (const float*)d_in[7];
  const float* b2        = (const float*)d_in[8];
  const float* w3        = (const float*)d_in[9];
  const float* b3        = (const float*)d_in[10];
  const float* w4        = (const float*)d_in[11];
  const float* b4        = (const float*)d_in[12];
  const float* wout      = (const float*)d_in[13];
  const float* bout      = (const float*)d_in[14];
  float* out = (float*)d_out;
  __bf16* ws = (__bf16*)d_ws;

  prep_kernel<<<(N_TOTAL + 255) / 256, 256, 0, stream>>>(fc, w1, w2, w3, w4, ws);
  fkan_inr_kernel<<<N_PTS / TILE, 512, 0, stream>>>(coords, fkan_bias, ln_g, ln_b,
                                                    b1, b2, b3, b4, wout, bout, ws, out);
}

// Round 5
// 649.342 us; speedup vs baseline: 2.1630x; 1.0038x over previous
//
#include <hip/hip_runtime.h>
#include <math.h>

#define N_PTS 131072
#define HID 256
#define H2 512
#define H4 1024
#define GRIDW 64
#define K1 384          // 2 * 3 * 64 fourier features
#define TILE 64         // points per block
#define LN_EPS 1e-5f
#define OMEGA 30.0f

typedef __bf16 b16x8 __attribute__((ext_vector_type(8)));
typedef __bf16 b16x4 __attribute__((ext_vector_type(4)));
typedef float f32x4 __attribute__((ext_vector_type(4)));

// bf16 weight workspace layout (element offsets)
#define OFF_FC 0
#define N_FC   (HID * K1)            // 98304   fcW[256][384]
#define OFF_W1 (OFF_FC + N_FC)       // 98304   w1[512][256]
#define N_W1   (H2 * HID)            // 131072
#define OFF_W2 (OFF_W1 + N_W1)       // 229376  w2[512][512]
#define N_W2   (H2 * H2)             // 262144
#define OFF_W3 (OFF_W2 + N_W2)       // 491520  w3[512][512]
#define OFF_W4 (OFF_W3 + N_W2)       // 753664  w4[1024][512]
#define N_W4   (H4 * H2)             // 524288
#define N_TOTAL (OFF_W4 + N_W4)      // 1277952 elements (~2.44 MB bf16)

// ---------------- weight bf16 prep ----------------
__global__ void prep_kernel(const float* __restrict__ fc, const float* __restrict__ w1,
                            const float* __restrict__ w2, const float* __restrict__ w3,
                            const float* __restrict__ w4, __bf16* __restrict__ ws) {
  int idx = blockIdx.x * blockDim.x + threadIdx.x;
  if (idx >= N_TOTAL) return;
  float v;
  if (idx < OFF_W1) {
    // fcW[o][k], k = s*192 + i*64 + g  <-  fc[s][o][i][g], fc shape (2,256,3,64)
    int o = idx / K1, r = idx % K1;
    int s = r / 192, rem = r % 192, i = rem / GRIDW, g = rem % GRIDW;
    v = fc[((s * HID + o) * 3 + i) * GRIDW + g];
  } else if (idx < OFF_W3) {
    v = (idx < OFF_W2) ? w1[idx - OFF_W1] : w2[idx - OFF_W2];
  } else {
    v = (idx < OFF_W4) ? w3[idx - OFF_W3] : w4[idx - OFF_W4];
  }
  ws[idx] = (__bf16)v;
}

// ---------------- fused INR kernel ----------------
// Single in-place LDS act tile: [64 points][<=512 ch] bf16, row stride 1024 B.
// XOR swizzle byte ^= ((n&7)<<4) at 16B granularity (T2) breaks the
// stride-1024B bank conflict on ds_read_b128 across 16 rows.
// Per layer: gemm (reads tile, acc in AGPRs) -> barrier -> actfn from acc ->
// write back to the SAME tile -> barrier.  NOTHING but acc lives across the
// first barrier: at launch_bounds(512,4) the budget is 128 regs/wave
// (64 AGPR acc + 64 arch), and any cross-barrier VGPR stash spills (r4: 62 MB
// scratch writes).  66 KB LDS -> 2 blocks/CU, 16 waves/CU.

// actfn(z) = (z + tanh(30 z)) * sigmoid(z), via v_exp_f32 / v_rcp_f32.
// tanh(x) = 1 - 2/(e^{2x}+1): exp2->inf gives rcp->0 -> +1; exp2->0 gives -1.
__device__ __forceinline__ float actfn(float z) {
  const float L2E = 1.4426950408889634f;
  float t2 = __builtin_amdgcn_exp2f((2.0f * OMEGA * L2E) * z);
  float th = 1.0f - 2.0f * __builtin_amdgcn_rcpf(t2 + 1.0f);
  float se = __builtin_amdgcn_exp2f(-L2E * z);
  float sg = __builtin_amdgcn_rcpf(1.0f + se);
  return (z + th) * sg;
}

// HW sincos: v_sin/v_cos take REVOLUTIONS. ang <= 64 rad = 10.2 rev, fract first.
__device__ __forceinline__ void fast_sincos(float ang, float* s, float* c) {
  const float INV2PI = 0.15915493667125702f;
  float r = __builtin_amdgcn_fractf(ang * INV2PI);
  *s = __builtin_amdgcn_sinf(r);
  *c = __builtin_amdgcn_cosf(r);
}

// C[n, o_base + 0..16*OT) for n in 0..63:  D = W . X^T via mfma(Wfrag, Xfrag)
// D layout: row = o = (lane>>4)*4 + reg (+16*ot), col = n = lane&15 (+16*nt)
template <int K, int OT>
__device__ __forceinline__ void gemm_kloop(const unsigned char* sX, const __bf16* __restrict__ W,
                                           int lane, int o_base, f32x4 (&acc)[OT][4]) {
  const int l15 = lane & 15, lh = lane >> 4;
  constexpr int NK = K / 32;
#pragma unroll 2
  for (int ks = 0; ks < NK; ++ks) {
    b16x8 xf[4];
#pragma unroll
    for (int nt = 0; nt < 4; ++nt) {
      int n = nt * 16 + l15;
      int kb = ks * 64 + (lh << 4);
      xf[nt] = *(const b16x8*)(sX + n * 1024 + (kb ^ ((n & 7) << 4)));
    }
    b16x8 wf[OT];
#pragma unroll
    for (int ot = 0; ot < OT; ++ot) {
      int o = o_base + ot * 16 + l15;
      wf[ot] = *(const b16x8*)(W + (size_t)o * K + ks * 32 + (lh << 3));
    }
#pragma unroll
    for (int ot = 0; ot < OT; ++ot)
#pragma unroll
      for (int nt = 0; nt < 4; ++nt)
        acc[ot][nt] = __builtin_amdgcn_mfma_f32_16x16x32_bf16(wf[ot], xf[nt], acc[ot][nt], 0, 0, 0);
  }
}

// one sine layer IN PLACE: read sAct (K ch), write sAct (512 ch). 8 waves * OT=4.
// actfn AFTER the barrier, straight from acc (AGPRs) -> no cross-barrier VGPRs.
template <int K>
__device__ __forceinline__ void sine_layer_ip(unsigned char* sAct,
                                              const __bf16* __restrict__ W,
                                              const float* __restrict__ bias, int lane, int wid) {
  f32x4 acc[4][4] = {};
  const int o_base = wid * 64;
  gemm_kloop<K, 4>(sAct, W, lane, o_base, acc);
  const int l15 = lane & 15, lh = lane >> 4;
  __syncthreads();  // all waves finished READING sAct
#pragma unroll
  for (int ot = 0; ot < 4; ++ot) {
    int o0 = o_base + ot * 16 + (lh << 2);
    f32x4 bia = *(const f32x4*)(bias + o0);
#pragma unroll
    for (int nt = 0; nt < 4; ++nt) {
      int n = nt * 16 + l15;
      b16x4 h;
      h[0] = (__bf16)actfn(acc[ot][nt][0] + bia[0]);
      h[1] = (__bf16)actfn(acc[ot][nt][1] + bia[1]);
      h[2] = (__bf16)actfn(acc[ot][nt][2] + bia[2]);
      h[3] = (__bf16)actfn(acc[ot][nt][3] + bia[3]);
      *(b16x4*)(sAct + n * 1024 + ((o0 * 2) ^ ((n & 7) << 4))) = h;
    }
  }
  __syncthreads();  // writes visible
}

__global__ __launch_bounds__(512, 4) void fkan_inr_kernel(
    const float* __restrict__ coords, const float* __restrict__ fkan_bias,
    const float* __restrict__ ln_g, const float* __restrict__ ln_b,
    const float* __restrict__ b1, const float* __restrict__ b2,
    const float* __restrict__ b3, const float* __restrict__ b4,
    const float* __restrict__ wout, const float* __restrict__ bout,
    const __bf16* __restrict__ ws, float* __restrict__ out) {
  __shared__ __align__(16) unsigned char sAct[TILE * 1024];
  __shared__ float sSum[TILE], sSqs[TILE];
  __shared__ float sOutF[TILE][4];

  const int tid = threadIdx.x;
  const int lane = tid & 63, wid = tid >> 6;
  const int l15 = lane & 15, lh = lane >> 4;
  const int base_n = blockIdx.x * TILE;

  // ---- Phase F: fourier features -> sAct[n][k], k<384 ; zero LN stats + out acc
  if (tid < TILE) {
    sSum[tid] = 0.f; sSqs[tid] = 0.f;
    sOutF[tid][0] = 0.f; sOutF[tid][1] = 0.f; sOutF[tid][2] = 0.f; sOutF[tid][3] = 0.f;
  }
#pragma unroll
  for (int p = 0; p < 3; ++p) {
    int id = tid + p * 512;               // 0..1535 = (n, i, gchunk of 8)
    int n = id / 24, rem = id % 24, i = rem >> 3, g0 = (rem & 7) * 8;
    float c = coords[(base_n + n) * 3 + i];
    b16x8 cv, sv;
#pragma unroll
    for (int j = 0; j < 8; ++j) {
      float ang = c * (float)(g0 + j + 1);
      float s, co;
      fast_sincos(ang, &s, &co);
      cv[j] = (__bf16)co;
      sv[j] = (__bf16)s;
    }
    int kc = (i * GRIDW + g0) * 2;
    *(b16x8*)(sAct + n * 1024 + (kc ^ ((n & 7) << 4))) = cv;
    int ks2 = (192 + i * GRIDW + g0) * 2;
    *(b16x8*)(sAct + n * 1024 + (ks2 ^ ((n & 7) << 4))) = sv;
  }
  __syncthreads();

  // ---- GEMM1 (384 -> 256) + fkan_bias + LayerNorm, in place
  {
    f32x4 acc[2][4] = {};
    const int o_base = wid * 32;
    gemm_kloop<K1, 2>(sAct, ws + OFF_FC, lane, o_base, acc);
#pragma unroll
    for (int ot = 0; ot < 2; ++ot) {
      int o0 = o_base + ot * 16 + (lh << 2);
      f32x4 bia = *(const f32x4*)(fkan_bias + o0);
#pragma unroll
      for (int nt = 0; nt < 4; ++nt) acc[ot][nt] += bia;
    }
#pragma unroll
    for (int nt = 0; nt < 4; ++nt) {
      float s = 0.f, q = 0.f;
#pragma unroll
      for (int ot = 0; ot < 2; ++ot)
#pragma unroll
        for (int r = 0; r < 4; ++r) { float z = acc[ot][nt][r]; s += z; q += z * z; }
      s += __shfl_xor(s, 16); q += __shfl_xor(q, 16);
      s += __shfl_xor(s, 32); q += __shfl_xor(q, 32);
      if (lane < 16) {
        atomicAdd(&sSum[nt * 16 + lane], s);
        atomicAdd(&sSqs[nt * 16 + lane], q);
      }
    }
    __syncthreads();  // stats ready AND all feature reads done
#pragma unroll
    for (int nt = 0; nt < 4; ++nt) {
      int n = nt * 16 + l15;
      float mu = sSum[n] * (1.f / HID);
      float var = sSqs[n] * (1.f / HID) - mu * mu;
      float rs = rsqrtf(var + LN_EPS);
#pragma unroll
      for (int ot = 0; ot < 2; ++ot) {
        int o0 = o_base + ot * 16 + (lh << 2);
        f32x4 g4 = *(const f32x4*)(ln_g + o0);
        f32x4 bb = *(const f32x4*)(ln_b + o0);
        b16x4 h;
        h[0] = (__bf16)((acc[ot][nt][0] - mu) * rs * g4[0] + bb[0]);
        h[1] = (__bf16)((acc[ot][nt][1] - mu) * rs * g4[1] + bb[1]);
        h[2] = (__bf16)((acc[ot][nt][2] - mu) * rs * g4[2] + bb[2]);
        h[3] = (__bf16)((acc[ot][nt][3] - mu) * rs * g4[3] + bb[3]);
        *(b16x4*)(sAct + n * 1024 + ((o0 * 2) ^ ((n & 7) << 4))) = h;
      }
    }
    __syncthreads();
  }

  // ---- sine layers 1..3 (in place)
  sine_layer_ip<HID>(sAct, ws + OFF_W1, b1, lane, wid);
  sine_layer_ip<H2>(sAct, ws + OFF_W2, b2, lane, wid);
  sine_layer_ip<H2>(sAct, ws + OFF_W3, b3, lane, wid);

  // ---- layer 4 (512 -> 1024) fused with output projection (1024 -> 3)
  {
#pragma unroll
    for (int pass = 0; pass < 2; ++pass) {
      f32x4 acc[4][4] = {};
      int o_base = pass * 512 + wid * 64;
      gemm_kloop<H2, 4>(sAct, ws + OFF_W4, lane, o_base, acc);
      float pj[4][3] = {};
#pragma unroll
      for (int ot = 0; ot < 4; ++ot) {
        int o0 = o_base + ot * 16 + (lh << 2);
        f32x4 bia = *(const f32x4*)(b4 + o0);
        f32x4 wo0 = *(const f32x4*)(wout + 0 * H4 + o0);
        f32x4 wo1 = *(const f32x4*)(wout + 1 * H4 + o0);
        f32x4 wo2 = *(const f32x4*)(wout + 2 * H4 + o0);
#pragma unroll
        for (int nt = 0; nt < 4; ++nt) {
          float a0 = actfn(acc[ot][nt][0] + bia[0]);
          float a1 = actfn(acc[ot][nt][1] + bia[1]);
          float a2 = actfn(acc[ot][nt][2] + bia[2]);
          float a3 = actfn(acc[ot][nt][3] + bia[3]);
          pj[nt][0] += a0 * wo0[0] + a1 * wo0[1] + a2 * wo0[2] + a3 * wo0[3];
          pj[nt][1] += a0 * wo1[0] + a1 * wo1[1] + a2 * wo1[2] + a3 * wo1[3];
          pj[nt][2] += a0 * wo2[0] + a1 * wo2[1] + a2 * wo2[2] + a3 * wo2[3];
        }
      }
#pragma unroll
      for (int nt = 0; nt < 4; ++nt)
#pragma unroll
        for (int j = 0; j < 3; ++j) {
          float r = pj[nt][j];
          r += __shfl_xor(r, 16);
          r += __shfl_xor(r, 32);
          if (lane < 16) atomicAdd(&sOutF[nt * 16 + lane][j], r);
        }
    }
    __syncthreads();
    if (tid < TILE * 3) {
      int n = tid / 3, j = tid % 3;
      out[(base_n + n) * 3 + j] = sOutF[n][j] + bout[j];
    }
  }
}

extern "C" void kernel_launch(void* const* d_in, const int* in_sizes, int n_in,
                              void* d_out, int out_size, void* d_ws, size_t ws_size,
                              hipStream_t stream) {
  const float* coords    = (const float*)d_in[0];
  const float* fc        = (const float*)d_in[1];
  const float* fkan_bias = (const float*)d_in[2];
  const float* ln_g      = (const float*)d_in[3];
  const float* ln_b      = (const float*)d_in[4];
  const float* w1        = (const float*)d_in[5];
  const float* b1        = (const float*)d_in[6];
  const float* w2        = (const float*)d_in[7];
  const float* b2        = (const float*)d_in[8];
  const float* w3        = (const float*)d_in[9];
  const float* b3        = (const float*)d_in[10];
  const float* w4        = (const float*)d_in[11];
  const float* b4        = (const float*)d_in[12];
  const float* wout      = (const float*)d_in[13];
  const float* bout      = (const float*)d_in[14];
  float* out = (float*)d_out;
  __bf16* ws = (__bf16*)d_ws;

  prep_kernel<<<(N_TOTAL + 255) / 256, 256, 0, stream>>>(fc, w1, w2, w3, w4, ws);
  fkan_inr_kernel<<<N_PTS / TILE, 512, 0, stream>>>(coords, fkan_bias, ln_g, ln_b,
                                                    b1, b2, b3, b4, wout, bout, ws, out);
}

// Round 6
// 396.987 us; speedup vs baseline: 3.5380x; 1.6357x over previous
//
#include <hip/hip_runtime.h>
#include <math.h>

#define N_PTS 131072
#define HID 256
#define H2 512
#define H4 1024
#define GRIDW 64
#define K1 384          // 2 * 3 * 64 fourier features
#define TILE 128        // points per block
#define LN_EPS 1e-5f
#define OMEGA 30.0f

typedef __bf16 b16x8 __attribute__((ext_vector_type(8)));
typedef __bf16 b16x4 __attribute__((ext_vector_type(4)));
typedef float f32x4 __attribute__((ext_vector_type(4)));

// ---- packed-fragment weight workspace (element offsets) ----
// Each weight matrix (O x K) is stored as chunks c = otile*NK + ks (NK = K/32),
// chunk = 512 elems: elem p: lane = p/8, j = p%8 ->
//   o = otile*16 + (lane&15), k = ks*32 + (lane>>4)*8 + j
// so a wave's fragment load is 16 B/lane fully contiguous (4 KB/chunk... 1KB/16 lanes).
#define OFF_FC 0
#define N_FC   (HID * K1)            // 98304
#define OFF_W1 (OFF_FC + N_FC)
#define N_W1   (H2 * HID)            // 131072
#define OFF_W2 (OFF_W1 + N_W1)
#define N_W2   (H2 * H2)             // 262144
#define OFF_W3 (OFF_W2 + N_W2)
#define OFF_W4 (OFF_W3 + N_W2)
#define N_W4   (H4 * H2)             // 524288
#define N_TOTAL (OFF_W4 + N_W4)      // 1277952 elements (~2.44 MB bf16)

__global__ void prep_kernel(const float* __restrict__ fc, const float* __restrict__ w1,
                            const float* __restrict__ w2, const float* __restrict__ w3,
                            const float* __restrict__ w4, __bf16* __restrict__ ws) {
  int idx = blockIdx.x * blockDim.x + threadIdx.x;
  if (idx >= N_TOTAL) return;
  int r, K, NK;
  const float* src = nullptr;
  int region;
  if (idx < OFF_W1)      { r = idx - OFF_FC; K = K1;  region = 0; }
  else if (idx < OFF_W2) { r = idx - OFF_W1; K = HID; src = w1; region = 1; }
  else if (idx < OFF_W3) { r = idx - OFF_W2; K = H2;  src = w2; region = 1; }
  else if (idx < OFF_W4) { r = idx - OFF_W3; K = H2;  src = w3; region = 1; }
  else                   { r = idx - OFF_W4; K = H2;  src = w4; region = 1; }
  NK = K / 32;
  int c = r >> 9, p = r & 511;
  int otile = c / NK, ks = c % NK;
  int lane = p >> 3, j = p & 7;
  int o = otile * 16 + (lane & 15);
  int k = ks * 32 + ((lane >> 4) << 3) + j;
  float v;
  if (region == 0) {
    // fc shape (2,256,3,64): k = s*192 + i*64 + g
    int s = k / 192, rem = k % 192, i = rem / GRIDW, g = rem % GRIDW;
    v = fc[((s * HID + o) * 3 + i) * GRIDW + g];
  } else {
    v = src[o * K + k];
  }
  ws[idx] = (__bf16)v;
}

// ---------------- fused INR kernel ----------------
// Single in-place LDS act tile: [128 points][<=512 ch] bf16, row stride 1024 B.
// XOR swizzle byte ^= ((n&15)<<4): 16 distinct 16B slots per quarter-wave ->
// conflict-free ds_read_b128 across rows.
// 1 block/CU (128 KB LDS), launch_bounds(512,2) -> 256 unified regs/wave:
// acc[4][8] = 128 AGPR + ~70 arch VGPR fits with ZERO spill (r1-r5: 60-560 MB
// scratch writebacks at the 128-reg budget were the dominant loss).

// actfn(z) = (z + tanh(30 z)) * sigmoid(z), via v_exp_f32 / v_rcp_f32.
__device__ __forceinline__ float actfn(float z) {
  const float L2E = 1.4426950408889634f;
  float t2 = __builtin_amdgcn_exp2f((2.0f * OMEGA * L2E) * z);
  float th = 1.0f - 2.0f * __builtin_amdgcn_rcpf(t2 + 1.0f);
  float se = __builtin_amdgcn_exp2f(-L2E * z);
  float sg = __builtin_amdgcn_rcpf(1.0f + se);
  return (z + th) * sg;
}

// HW sincos: v_sin/v_cos take REVOLUTIONS. ang <= 64 rad = 10.2 rev, fract first.
__device__ __forceinline__ void fast_sincos(float ang, float* s, float* c) {
  const float INV2PI = 0.15915493667125702f;
  float r = __builtin_amdgcn_fractf(ang * INV2PI);
  *s = __builtin_amdgcn_sinf(r);
  *c = __builtin_amdgcn_cosf(r);
}

#define SWZ(n) (((n) & 15) << 4)

// D = W . X^T via mfma(Wfrag, Xfrag): row = o = (lane>>4)*4+reg (+16*ot),
// col = n = lane&15 (+16*nt).  W is packed-fragment (see prep_kernel).
template <int K, int OT>
__device__ __forceinline__ void gemm_kloop(const unsigned char* sX, const __bf16* __restrict__ W,
                                           int lane, int o_base, f32x4 (&acc)[OT][8]) {
  const int l15 = lane & 15, lh = lane >> 4;
  constexpr int NK = K / 32;
#pragma unroll 1
  for (int ks = 0; ks < NK; ++ks) {
    b16x8 xf[8];
#pragma unroll
    for (int nt = 0; nt < 8; ++nt) {
      int n = nt * 16 + l15;
      int kb = ks * 64 + (lh << 4);
      xf[nt] = *(const b16x8*)(sX + n * 1024 + (kb ^ SWZ(n)));
    }
    b16x8 wf[OT];
#pragma unroll
    for (int ot = 0; ot < OT; ++ot) {
      int chunk = (o_base / 16 + ot) * NK + ks;
      wf[ot] = *(const b16x8*)(W + (size_t)chunk * 512 + lane * 8);
    }
#pragma unroll
    for (int ot = 0; ot < OT; ++ot)
#pragma unroll
      for (int nt = 0; nt < 8; ++nt)
        acc[ot][nt] = __builtin_amdgcn_mfma_f32_16x16x32_bf16(wf[ot], xf[nt], acc[ot][nt], 0, 0, 0);
  }
}

// one sine layer IN PLACE: read sAct (K ch), write sAct (512 ch). 8 waves * OT=4.
template <int K>
__device__ __forceinline__ void sine_layer_ip(unsigned char* sAct,
                                              const __bf16* __restrict__ W,
                                              const float* __restrict__ bias, int lane, int wid) {
  f32x4 acc[4][8] = {};
  const int o_base = wid * 64;
  gemm_kloop<K, 4>(sAct, W, lane, o_base, acc);
  const int l15 = lane & 15, lh = lane >> 4;
  __syncthreads();  // all waves finished READING sAct
#pragma unroll
  for (int ot = 0; ot < 4; ++ot) {
    int o0 = o_base + ot * 16 + (lh << 2);
    f32x4 bia = *(const f32x4*)(bias + o0);
#pragma unroll
    for (int nt = 0; nt < 8; ++nt) {
      int n = nt * 16 + l15;
      b16x4 h;
      h[0] = (__bf16)actfn(acc[ot][nt][0] + bia[0]);
      h[1] = (__bf16)actfn(acc[ot][nt][1] + bia[1]);
      h[2] = (__bf16)actfn(acc[ot][nt][2] + bia[2]);
      h[3] = (__bf16)actfn(acc[ot][nt][3] + bia[3]);
      *(b16x4*)(sAct + n * 1024 + ((o0 * 2) ^ SWZ(n))) = h;
    }
  }
  __syncthreads();  // writes visible
}

__global__ __launch_bounds__(512, 2) void fkan_inr_kernel(
    const float* __restrict__ coords, const float* __restrict__ fkan_bias,
    const float* __restrict__ ln_g, const float* __restrict__ ln_b,
    const float* __restrict__ b1, const float* __restrict__ b2,
    const float* __restrict__ b3, const float* __restrict__ b4,
    const float* __restrict__ wout, const float* __restrict__ bout,
    const __bf16* __restrict__ ws, float* __restrict__ out) {
  __shared__ __align__(16) unsigned char sAct[TILE * 1024];   // 128 KB
  __shared__ float sSum[TILE], sSqs[TILE];
  __shared__ float sOutF[TILE][4];

  const int tid = threadIdx.x;
  const int lane = tid & 63, wid = tid >> 6;
  const int l15 = lane & 15, lh = lane >> 4;
  const int base_n = blockIdx.x * TILE;

  // ---- Phase F: fourier features -> sAct[n][k], k<384 ; zero LN stats + out acc
  if (tid < TILE) {
    sSum[tid] = 0.f; sSqs[tid] = 0.f;
    sOutF[tid][0] = 0.f; sOutF[tid][1] = 0.f; sOutF[tid][2] = 0.f; sOutF[tid][3] = 0.f;
  }
#pragma unroll
  for (int p = 0; p < 6; ++p) {
    int id = tid + p * 512;               // 0..3071 = (n, i, gchunk of 8)
    int n = id / 24, rem = id % 24, i = rem >> 3, g0 = (rem & 7) * 8;
    float c = coords[(base_n + n) * 3 + i];
    b16x8 cv, sv;
#pragma unroll
    for (int j = 0; j < 8; ++j) {
      float ang = c * (float)(g0 + j + 1);
      float s, co;
      fast_sincos(ang, &s, &co);
      cv[j] = (__bf16)co;
      sv[j] = (__bf16)s;
    }
    int kc = (i * GRIDW + g0) * 2;
    *(b16x8*)(sAct + n * 1024 + (kc ^ SWZ(n))) = cv;
    int ks2 = (192 + i * GRIDW + g0) * 2;
    *(b16x8*)(sAct + n * 1024 + (ks2 ^ SWZ(n))) = sv;
  }
  __syncthreads();

  // ---- GEMM1 (384 -> 256) + fkan_bias + LayerNorm, in place
  {
    f32x4 acc[2][8] = {};
    const int o_base = wid * 32;
    gemm_kloop<K1, 2>(sAct, ws + OFF_FC, lane, o_base, acc);
#pragma unroll
    for (int ot = 0; ot < 2; ++ot) {
      int o0 = o_base + ot * 16 + (lh << 2);
      f32x4 bia = *(const f32x4*)(fkan_bias + o0);
#pragma unroll
      for (int nt = 0; nt < 8; ++nt) acc[ot][nt] += bia;
    }
#pragma unroll
    for (int nt = 0; nt < 8; ++nt) {
      float s = 0.f, q = 0.f;
#pragma unroll
      for (int ot = 0; ot < 2; ++ot)
#pragma unroll
        for (int r = 0; r < 4; ++r) { float z = acc[ot][nt][r]; s += z; q += z * z; }
      s += __shfl_xor(s, 16); q += __shfl_xor(q, 16);
      s += __shfl_xor(s, 32); q += __shfl_xor(q, 32);
      if (lane < 16) {
        atomicAdd(&sSum[nt * 16 + lane], s);
        atomicAdd(&sSqs[nt * 16 + lane], q);
      }
    }
    __syncthreads();  // stats ready AND all feature reads done
#pragma unroll
    for (int nt = 0; nt < 8; ++nt) {
      int n = nt * 16 + l15;
      float mu = sSum[n] * (1.f / HID);
      float var = sSqs[n] * (1.f / HID) - mu * mu;
      float rs = rsqrtf(var + LN_EPS);
#pragma unroll
      for (int ot = 0; ot < 2; ++ot) {
        int o0 = o_base + ot * 16 + (lh << 2);
        f32x4 g4 = *(const f32x4*)(ln_g + o0);
        f32x4 bb = *(const f32x4*)(ln_b + o0);
        b16x4 h;
        h[0] = (__bf16)((acc[ot][nt][0] - mu) * rs * g4[0] + bb[0]);
        h[1] = (__bf16)((acc[ot][nt][1] - mu) * rs * g4[1] + bb[1]);
        h[2] = (__bf16)((acc[ot][nt][2] - mu) * rs * g4[2] + bb[2]);
        h[3] = (__bf16)((acc[ot][nt][3] - mu) * rs * g4[3] + bb[3]);
        *(b16x4*)(sAct + n * 1024 + ((o0 * 2) ^ SWZ(n))) = h;
      }
    }
    __syncthreads();
  }

  // ---- sine layers 1..3 (in place)
  sine_layer_ip<HID>(sAct, ws + OFF_W1, b1, lane, wid);
  sine_layer_ip<H2>(sAct, ws + OFF_W2, b2, lane, wid);
  sine_layer_ip<H2>(sAct, ws + OFF_W3, b3, lane, wid);

  // ---- layer 4 (512 -> 1024) fused with output projection (1024 -> 3)
  {
#pragma unroll 1
    for (int pass = 0; pass < 2; ++pass) {
      f32x4 acc[4][8] = {};
      int o_base = pass * 512 + wid * 64;
      gemm_kloop<H2, 4>(sAct, ws + OFF_W4, lane, o_base, acc);
      float pj[8][3] = {};
#pragma unroll
      for (int ot = 0; ot < 4; ++ot) {
        int o0 = o_base + ot * 16 + (lh << 2);
        f32x4 bia = *(const f32x4*)(b4 + o0);
        f32x4 wo0 = *(const f32x4*)(wout + 0 * H4 + o0);
        f32x4 wo1 = *(const f32x4*)(wout + 1 * H4 + o0);
        f32x4 wo2 = *(const f32x4*)(wout + 2 * H4 + o0);
#pragma unroll
        for (int nt = 0; nt < 8; ++nt) {
          float a0 = actfn(acc[ot][nt][0] + bia[0]);
          float a1 = actfn(acc[ot][nt][1] + bia[1]);
          float a2 = actfn(acc[ot][nt][2] + bia[2]);
          float a3 = actfn(acc[ot][nt][3] + bia[3]);
          pj[nt][0] += a0 * wo0[0] + a1 * wo0[1] + a2 * wo0[2] + a3 * wo0[3];
          pj[nt][1] += a0 * wo1[0] + a1 * wo1[1] + a2 * wo1[2] + a3 * wo1[3];
          pj[nt][2] += a0 * wo2[0] + a1 * wo2[1] + a2 * wo2[2] + a3 * wo2[3];
        }
      }
#pragma unroll
      for (int nt = 0; nt < 8; ++nt)
#pragma unroll
        for (int j = 0; j < 3; ++j) {
          float r = pj[nt][j];
          r += __shfl_xor(r, 16);
          r += __shfl_xor(r, 32);
          if (lane < 16) atomicAdd(&sOutF[nt * 16 + lane][j], r);
        }
    }
    __syncthreads();
    if (tid < TILE * 3) {
      int n = tid / 3, j = tid % 3;
      out[(base_n + n) * 3 + j] = sOutF[n][j] + bout[j];
    }
  }
}

extern "C" void kernel_launch(void* const* d_in, const int* in_sizes, int n_in,
                              void* d_out, int out_size, void* d_ws, size_t ws_size,
                              hipStream_t stream) {
  const float* coords    = (const float*)d_in[0];
  const float* fc        = (const float*)d_in[1];
  const float* fkan_bias = (const float*)d_in[2];
  const float* ln_g      = (const float*)d_in[3];
  const float* ln_b      = (const float*)d_in[4];
  const float* w1        = (const float*)d_in[5];
  const float* b1        = (const float*)d_in[6];
  const float* w2        = (const float*)d_in[7];
  const float* b2        = (const float*)d_in[8];
  const float* w3        = (const float*)d_in[9];
  const float* b3        = (const float*)d_in[10];
  const float* w4        = (const float*)d_in[11];
  const float* b4        = (const float*)d_in[12];
  const float* wout      = (const float*)d_in[13];
  const float* bout      = (const float*)d_in[14];
  float* out = (float*)d_out;
  __bf16* ws = (__bf16*)d_ws;

  prep_kernel<<<(N_TOTAL + 255) / 256, 256, 0, stream>>>(fc, w1, w2, w3, w4, ws);
  fkan_inr_kernel<<<N_PTS / TILE, 512, 0, stream>>>(coords, fkan_bias, ln_g, ln_b,
                                                    b1, b2, b3, b4, wout, bout, ws, out);
}

// Round 7
// 392.716 us; speedup vs baseline: 3.5764x; 1.0109x over previous
//
#include <hip/hip_runtime.h>
#include <math.h>

#define N_PTS 131072
#define HID 256
#define H2 512
#define H4 1024
#define GRIDW 64
#define K1 384          // 2 * 3 * 64 fourier features
#define TILE 128        // points per block
#define LN_EPS 1e-5f
#define OMEGA 30.0f

typedef __bf16 b16x8 __attribute__((ext_vector_type(8)));
typedef __bf16 b16x4 __attribute__((ext_vector_type(4)));
typedef float f32x4 __attribute__((ext_vector_type(4)));

// ---- packed-fragment weight workspace (element offsets) ----
// Each weight matrix (O x K) is stored as chunks c = otile*NK + ks (NK = K/32),
// chunk = 512 elems: elem p: lane = p/8, j = p%8 ->
//   o = otile*16 + (lane&15), k = ks*32 + (lane>>4)*8 + j
// so a wave's fragment load is 16 B/lane fully contiguous.
#define OFF_FC 0
#define N_FC   (HID * K1)            // 98304
#define OFF_W1 (OFF_FC + N_FC)
#define N_W1   (H2 * HID)            // 131072
#define OFF_W2 (OFF_W1 + N_W1)
#define N_W2   (H2 * H2)             // 262144
#define OFF_W3 (OFF_W2 + N_W2)
#define OFF_W4 (OFF_W3 + N_W2)
#define N_W4   (H4 * H2)             // 524288
#define N_TOTAL (OFF_W4 + N_W4)      // 1277952 elements (~2.44 MB bf16)

__global__ void prep_kernel(const float* __restrict__ fc, const float* __restrict__ w1,
                            const float* __restrict__ w2, const float* __restrict__ w3,
                            const float* __restrict__ w4, __bf16* __restrict__ ws) {
  int idx = blockIdx.x * blockDim.x + threadIdx.x;
  if (idx >= N_TOTAL) return;
  int r, K, NK;
  const float* src = nullptr;
  int region;
  if (idx < OFF_W1)      { r = idx - OFF_FC; K = K1;  region = 0; }
  else if (idx < OFF_W2) { r = idx - OFF_W1; K = HID; src = w1; region = 1; }
  else if (idx < OFF_W3) { r = idx - OFF_W2; K = H2;  src = w2; region = 1; }
  else if (idx < OFF_W4) { r = idx - OFF_W3; K = H2;  src = w3; region = 1; }
  else                   { r = idx - OFF_W4; K = H2;  src = w4; region = 1; }
  NK = K / 32;
  int c = r >> 9, p = r & 511;
  int otile = c / NK, ks = c % NK;
  int lane = p >> 3, j = p & 7;
  int o = otile * 16 + (lane & 15);
  int k = ks * 32 + ((lane >> 4) << 3) + j;
  float v;
  if (region == 0) {
    // fc shape (2,256,3,64): k = s*192 + i*64 + g
    int s = k / 192, rem = k % 192, i = rem / GRIDW, g = rem % GRIDW;
    v = fc[((s * HID + o) * 3 + i) * GRIDW + g];
  } else {
    v = src[o * K + k];
  }
  ws[idx] = (__bf16)v;
}

// ---------------- fused INR kernel ----------------
// Single in-place LDS act tile: [128 points][<=512 ch] bf16, row stride 1024 B.
// XOR swizzle byte ^= ((n&15)<<4). 1 block/CU, launch_bounds(512,2):
// 256 unified regs/wave = 128 AGPR acc + ~110 arch VGPR + 16 W-prefetch.

// actfn(z) = (z + tanh(30 z)) * sigmoid(z), via v_exp_f32 / v_rcp_f32.
__device__ __forceinline__ float actfn(float z) {
  const float L2E = 1.4426950408889634f;
  float t2 = __builtin_amdgcn_exp2f((2.0f * OMEGA * L2E) * z);
  float th = 1.0f - 2.0f * __builtin_amdgcn_rcpf(t2 + 1.0f);
  float se = __builtin_amdgcn_exp2f(-L2E * z);
  float sg = __builtin_amdgcn_rcpf(1.0f + se);
  return (z + th) * sg;
}

// HW sincos: v_sin/v_cos take REVOLUTIONS. ang <= 64 rad = 10.2 rev, fract first.
__device__ __forceinline__ void fast_sincos(float ang, float* s, float* c) {
  const float INV2PI = 0.15915493667125702f;
  float r = __builtin_amdgcn_fractf(ang * INV2PI);
  *s = __builtin_amdgcn_sinf(r);
  *c = __builtin_amdgcn_cosf(r);
}

#define SWZ(n) (((n) & 15) << 4)

// D = W . X^T via mfma(Wfrag, Xfrag): row = o = (lane>>4)*4+reg (+16*ot),
// col = n = lane&15 (+16*nt).  W is packed-fragment (see prep_kernel).
// 1-deep cross-ks W prefetch: wf(ks+1) loads (L2, ~200-400 cyc) issue before
// the ks MFMA block, so the vmcnt wait lands after ~155 cyc of MFMA work and
// the second wave on the SIMD covers the rest.  xf stays unprefetched (LDS
// latency is short and 8 reads pipeline).
template <int K, int OT>
__device__ __forceinline__ void gemm_kloop(const unsigned char* sX, const __bf16* __restrict__ W,
                                           int lane, int o_base, f32x4 (&acc)[OT][8]) {
  const int l15 = lane & 15, lh = lane >> 4;
  constexpr int NK = K / 32;
  b16x8 wf[OT];
#pragma unroll
  for (int ot = 0; ot < OT; ++ot)
    wf[ot] = *(const b16x8*)(W + (size_t)((o_base / 16 + ot) * NK) * 512 + lane * 8);
#pragma unroll 1
  for (int ks = 0; ks < NK; ++ks) {
    b16x8 xf[8];
#pragma unroll
    for (int nt = 0; nt < 8; ++nt) {
      int n = nt * 16 + l15;
      int kb = ks * 64 + (lh << 4);
      xf[nt] = *(const b16x8*)(sX + n * 1024 + (kb ^ SWZ(n)));
    }
    b16x8 wn[OT];
    if (ks + 1 < NK) {
#pragma unroll
      for (int ot = 0; ot < OT; ++ot)
        wn[ot] = *(const b16x8*)(W + (size_t)((o_base / 16 + ot) * NK + ks + 1) * 512 + lane * 8);
    }
#pragma unroll
    for (int ot = 0; ot < OT; ++ot)
#pragma unroll
      for (int nt = 0; nt < 8; ++nt)
        acc[ot][nt] = __builtin_amdgcn_mfma_f32_16x16x32_bf16(wf[ot], xf[nt], acc[ot][nt], 0, 0, 0);
#pragma unroll
    for (int ot = 0; ot < OT; ++ot) wf[ot] = wn[ot];
  }
}

// one sine layer IN PLACE: read sAct (K ch), write sAct (512 ch). 8 waves * OT=4.
template <int K>
__device__ __forceinline__ void sine_layer_ip(unsigned char* sAct,
                                              const __bf16* __restrict__ W,
                                              const float* __restrict__ bias, int lane, int wid) {
  f32x4 acc[4][8] = {};
  const int o_base = wid * 64;
  gemm_kloop<K, 4>(sAct, W, lane, o_base, acc);
  const int l15 = lane & 15, lh = lane >> 4;
  __syncthreads();  // all waves finished READING sAct
#pragma unroll
  for (int ot = 0; ot < 4; ++ot) {
    int o0 = o_base + ot * 16 + (lh << 2);
    f32x4 bia = *(const f32x4*)(bias + o0);
#pragma unroll
    for (int nt = 0; nt < 8; ++nt) {
      int n = nt * 16 + l15;
      b16x4 h;
      h[0] = (__bf16)actfn(acc[ot][nt][0] + bia[0]);
      h[1] = (__bf16)actfn(acc[ot][nt][1] + bia[1]);
      h[2] = (__bf16)actfn(acc[ot][nt][2] + bia[2]);
      h[3] = (__bf16)actfn(acc[ot][nt][3] + bia[3]);
      *(b16x4*)(sAct + n * 1024 + ((o0 * 2) ^ SWZ(n))) = h;
    }
  }
  __syncthreads();  // writes visible
}

__global__ __launch_bounds__(512, 2) void fkan_inr_kernel(
    const float* __restrict__ coords, const float* __restrict__ fkan_bias,
    const float* __restrict__ ln_g, const float* __restrict__ ln_b,
    const float* __restrict__ b1, const float* __restrict__ b2,
    const float* __restrict__ b3, const float* __restrict__ b4,
    const float* __restrict__ wout, const float* __restrict__ bout,
    const __bf16* __restrict__ ws, float* __restrict__ out) {
  __shared__ __align__(16) unsigned char sAct[TILE * 1024];   // 128 KB
  __shared__ float sSum[TILE], sSqs[TILE];
  __shared__ float sOutF[TILE][4];

  const int tid = threadIdx.x;
  const int lane = tid & 63, wid = tid >> 6;
  const int l15 = lane & 15, lh = lane >> 4;
  const int base_n = blockIdx.x * TILE;

  // ---- Phase F: fourier features -> sAct[n][k], k<384 ; zero LN stats + out acc
  if (tid < TILE) {
    sSum[tid] = 0.f; sSqs[tid] = 0.f;
    sOutF[tid][0] = 0.f; sOutF[tid][1] = 0.f; sOutF[tid][2] = 0.f; sOutF[tid][3] = 0.f;
  }
#pragma unroll
  for (int p = 0; p < 6; ++p) {
    int id = tid + p * 512;               // 0..3071 = (n, i, gchunk of 8)
    int n = id / 24, rem = id % 24, i = rem >> 3, g0 = (rem & 7) * 8;
    float c = coords[(base_n + n) * 3 + i];
    b16x8 cv, sv;
#pragma unroll
    for (int j = 0; j < 8; ++j) {
      float ang = c * (float)(g0 + j + 1);
      float s, co;
      fast_sincos(ang, &s, &co);
      cv[j] = (__bf16)co;
      sv[j] = (__bf16)s;
    }
    int kc = (i * GRIDW + g0) * 2;
    *(b16x8*)(sAct + n * 1024 + (kc ^ SWZ(n))) = cv;
    int ks2 = (192 + i * GRIDW + g0) * 2;
    *(b16x8*)(sAct + n * 1024 + (ks2 ^ SWZ(n))) = sv;
  }
  __syncthreads();

  // ---- GEMM1 (384 -> 256) + fkan_bias + LayerNorm, in place
  {
    f32x4 acc[2][8] = {};
    const int o_base = wid * 32;
    gemm_kloop<K1, 2>(sAct, ws + OFF_FC, lane, o_base, acc);
#pragma unroll
    for (int ot = 0; ot < 2; ++ot) {
      int o0 = o_base + ot * 16 + (lh << 2);
      f32x4 bia = *(const f32x4*)(fkan_bias + o0);
#pragma unroll
      for (int nt = 0; nt < 8; ++nt) acc[ot][nt] += bia;
    }
#pragma unroll
    for (int nt = 0; nt < 8; ++nt) {
      float s = 0.f, q = 0.f;
#pragma unroll
      for (int ot = 0; ot < 2; ++ot)
#pragma unroll
        for (int r = 0; r < 4; ++r) { float z = acc[ot][nt][r]; s += z; q += z * z; }
      s += __shfl_xor(s, 16); q += __shfl_xor(q, 16);
      s += __shfl_xor(s, 32); q += __shfl_xor(q, 32);
      if (lane < 16) {
        atomicAdd(&sSum[nt * 16 + lane], s);
        atomicAdd(&sSqs[nt * 16 + lane], q);
      }
    }
    __syncthreads();  // stats ready AND all feature reads done
#pragma unroll
    for (int nt = 0; nt < 8; ++nt) {
      int n = nt * 16 + l15;
      float mu = sSum[n] * (1.f / HID);
      float var = sSqs[n] * (1.f / HID) - mu * mu;
      float rs = rsqrtf(var + LN_EPS);
#pragma unroll
      for (int ot = 0; ot < 2; ++ot) {
        int o0 = o_base + ot * 16 + (lh << 2);
        f32x4 g4 = *(const f32x4*)(ln_g + o0);
        f32x4 bb = *(const f32x4*)(ln_b + o0);
        b16x4 h;
        h[0] = (__bf16)((acc[ot][nt][0] - mu) * rs * g4[0] + bb[0]);
        h[1] = (__bf16)((acc[ot][nt][1] - mu) * rs * g4[1] + bb[1]);
        h[2] = (__bf16)((acc[ot][nt][2] - mu) * rs * g4[2] + bb[2]);
        h[3] = (__bf16)((acc[ot][nt][3] - mu) * rs * g4[3] + bb[3]);
        *(b16x4*)(sAct + n * 1024 + ((o0 * 2) ^ SWZ(n))) = h;
      }
    }
    __syncthreads();
  }

  // ---- sine layers 1..3 (in place)
  sine_layer_ip<HID>(sAct, ws + OFF_W1, b1, lane, wid);
  sine_layer_ip<H2>(sAct, ws + OFF_W2, b2, lane, wid);
  sine_layer_ip<H2>(sAct, ws + OFF_W3, b3, lane, wid);

  // ---- layer 4 (512 -> 1024) fused with output projection (1024 -> 3)
  {
#pragma unroll 1
    for (int pass = 0; pass < 2; ++pass) {
      f32x4 acc[4][8] = {};
      int o_base = pass * 512 + wid * 64;
      gemm_kloop<H2, 4>(sAct, ws + OFF_W4, lane, o_base, acc);
      float pj[8][3] = {};
#pragma unroll
      for (int ot = 0; ot < 4; ++ot) {
        int o0 = o_base + ot * 16 + (lh << 2);
        f32x4 bia = *(const f32x4*)(b4 + o0);
        f32x4 wo0 = *(const f32x4*)(wout + 0 * H4 + o0);
        f32x4 wo1 = *(const f32x4*)(wout + 1 * H4 + o0);
        f32x4 wo2 = *(const f32x4*)(wout + 2 * H4 + o0);
#pragma unroll
        for (int nt = 0; nt < 8; ++nt) {
          float a0 = actfn(acc[ot][nt][0] + bia[0]);
          float a1 = actfn(acc[ot][nt][1] + bia[1]);
          float a2 = actfn(acc[ot][nt][2] + bia[2]);
          float a3 = actfn(acc[ot][nt][3] + bia[3]);
          pj[nt][0] += a0 * wo0[0] + a1 * wo0[1] + a2 * wo0[2] + a3 * wo0[3];
          pj[nt][1] += a0 * wo1[0] + a1 * wo1[1] + a2 * wo1[2] + a3 * wo1[3];
          pj[nt][2] += a0 * wo2[0] + a1 * wo2[1] + a2 * wo2[2] + a3 * wo2[3];
        }
      }
#pragma unroll
      for (int nt = 0; nt < 8; ++nt)
#pragma unroll
        for (int j = 0; j < 3; ++j) {
          float r = pj[nt][j];
          r += __shfl_xor(r, 16);
          r += __shfl_xor(r, 32);
          if (lane < 16) atomicAdd(&sOutF[nt * 16 + lane][j], r);
        }
    }
    __syncthreads();
    if (tid < TILE * 3) {
      int n = tid / 3, j = tid % 3;
      out[(base_n + n) * 3 + j] = sOutF[n][j] + bout[j];
    }
  }
}

extern "C" void kernel_launch(void* const* d_in, const int* in_sizes, int n_in,
                              void* d_out, int out_size, void* d_ws, size_t ws_size,
                              hipStream_t stream) {
  const float* coords    = (const float*)d_in[0];
  const float* fc        = (const float*)d_in[1];
  const float* fkan_bias = (const float*)d_in[2];
  const float* ln_g      = (const float*)d_in[3];
  const float* ln_b      = (const float*)d_in[4];
  const float* w1        = (const float*)d_in[5];
  const float* b1        = (const float*)d_in[6];
  const float* w2        = (const float*)d_in[7];
  const float* b2        = (const float*)d_in[8];
  const float* w3        = (const float*)d_in[9];
  const float* b3        = (const float*)d_in[10];
  const float* w4        = (const float*)d_in[11];
  const float* b4        = (const float*)d_in[12];
  const float* wout      = (const float*)d_in[13];
  const float* bout      = (const float*)d_in[14];
  float* out = (float*)d_out;
  __bf16* ws = (__bf16*)d_ws;

  prep_kernel<<<(N_TOTAL + 255) / 256, 256, 0, stream>>>(fc, w1, w2, w3, w4, ws);
  fkan_inr_kernel<<<N_PTS / TILE, 512, 0, stream>>>(coords, fkan_bias, ln_g, ln_b,
                                                    b1, b2, b3, b4, wout, bout, ws, out);
}